// Round 1
// baseline (2884.752 us; speedup 1.0000x reference)
//
#include <hip/hip_runtime.h>
#include <stdint.h>

// ---------------------------------------------------------------------------
// Dueling-DQN forward on MI355X. Strategy: everything bf16 MFMA (16x16x32),
// activations in NHWC bf16 so fragment loads are contiguous 16B, weights
// pre-packed to [cout][kh][kw][cin] bf16. No LDS in round 1 (rely on L1/L2);
// flat-pixel M tiling avoids padding waste.
// ---------------------------------------------------------------------------

using bf16_t = __bf16;
using bf16x8 = __attribute__((ext_vector_type(8))) __bf16;
using bf16x4 = __attribute__((ext_vector_type(4))) __bf16;
using f32x4  = __attribute__((ext_vector_type(4))) float;

__device__ __forceinline__ f32x4 mfma16(bf16x8 a, bf16x8 b, f32x4 c) {
    return __builtin_amdgcn_mfma_f32_16x16x32_bf16(a, b, c, 0, 0, 0);
}

template<bool A16>
__device__ __forceinline__ bf16x8 load_frag(const bf16_t* p) {
    if constexpr (A16) {
        return *reinterpret_cast<const bf16x8*>(p);
    } else {
        union { bf16x8 v; uint64_t u[2]; } r;
        r.u[0] = *reinterpret_cast<const uint64_t*>(p);
        r.u[1] = *reinterpret_cast<const uint64_t*>(p + 4);
        return r.v;
    }
}

// ---------------------------------------------------------------------------
// Weight pack / layout-convert: dst[cout][khw][cin] = (bf16)src[cout][cin][khw]
// Also used for NCHW->NHWC input conversion (COUT=batch, KK=H*W, CIN=C) and
// fc3 plain f32->bf16 copy (CIN=1).
// ---------------------------------------------------------------------------
template<int CIN>
__global__ void pack_w(const float* __restrict__ src, bf16_t* __restrict__ dst,
                       int COUT, int KK) {
    int total = COUT * KK;
    for (int t = blockIdx.x * blockDim.x + threadIdx.x; t < total;
         t += gridDim.x * blockDim.x) {
        int cout = t / KK;
        int khw  = t - cout * KK;
        alignas(16) bf16_t tmp[CIN];
        #pragma unroll
        for (int c = 0; c < CIN; ++c)
            tmp[c] = (bf16_t)src[((size_t)cout * CIN + c) * KK + khw];
        bf16_t* d = dst + (size_t)t * CIN;
        if constexpr (CIN == 1) {
            d[0] = tmp[0];
        } else if constexpr (CIN == 4) {
            *reinterpret_cast<uint2*>(d) = *reinterpret_cast<const uint2*>(tmp);
        } else {
            #pragma unroll
            for (int c = 0; c < CIN; c += 8)
                *reinterpret_cast<uint4*>(d + c) =
                    *reinterpret_cast<const uint4*>(tmp + c);
        }
    }
}

// scalar = relu(fc1(concat(g[0],v[0]))[30])  -- the only surviving fc1 value
__global__ void fc1_scalar(const float* __restrict__ g, const float* __restrict__ v,
                           const float* __restrict__ w, const float* __restrict__ b,
                           float* __restrict__ outp) {
    if (threadIdx.x == 0 && blockIdx.x == 0) {
        float s = b[30] + g[0] * w[120] + g[1] * w[121] + v[0] * w[122] + v[1] * w[123];
        *outp = s > 0.f ? s : 0.f;
    }
}

// ---------------------------------------------------------------------------
// Implicit-GEMM conv, VALID, stride 1, square images.
//   in : [B][W][W][CIN]  NHWC bf16
//   wp : [COUT][K][K][CIN] bf16 (k-order kh,kw,cin)
//   out: [B][OW][OW][COUT] NHWC bf16,  out = relu(conv+bias) (+scalar)
// MFMA A = weights (row=cout), B = pixels (col=flat output pixel).
// Each wave: WMT M-tiles (16 px each) x NT N-tiles (16 cout). 4 waves/block
// stacked along M.
// ---------------------------------------------------------------------------
template<int CIN, int COUT, int W, int K, int OW, int NBLK, int WMT,
         int ADD_SCALAR, bool A16>
__global__ __launch_bounds__(256, 2) void conv_mfma(
    const bf16_t* __restrict__ in, const bf16_t* __restrict__ wp,
    const float* __restrict__ bias, bf16_t* __restrict__ out,
    const float* __restrict__ scal) {
    constexpr int P    = OW * OW;
    constexpr int KCIN = K * CIN;        // K-elems per kh row
    constexpr int KTOT = K * KCIN;
    constexpr int RS   = KCIN / 32;      // MFMA K-steps per kh row
    constexpr int NT   = NBLK / 16;
    constexpr int BMT  = WMT * 4;

    const int b     = blockIdx.z;
    const int cout0 = blockIdx.y * NBLK;
    const int wave  = threadIdx.x >> 6;
    const int lane  = threadIdx.x & 63;
    const int l15   = lane & 15;
    const int l4    = lane >> 4;
    const int mt0   = blockIdx.x * BMT + wave * WMT;

    const bf16_t* inb = in + (size_t)b * (W * W * CIN);

    int      pix[WMT];
    uint32_t pb[WMT];
    #pragma unroll
    for (int m = 0; m < WMT; ++m) {
        int p  = (mt0 + m) * 16 + l15;
        pix[m] = p;
        int pc = p < P ? p : P - 1;      // clamp padded lanes to a valid pixel
        int oh = pc / OW;
        int ow = pc - oh * OW;
        pb[m]  = (uint32_t)(oh * W + ow) * CIN;
    }
    uint32_t wb[NT];
    #pragma unroll
    for (int n = 0; n < NT; ++n)
        wb[n] = (uint32_t)(cout0 + n * 16 + l15) * KTOT + (uint32_t)l4 * 8u;

    f32x4 acc[WMT][NT];
    #pragma unroll
    for (int m = 0; m < WMT; ++m)
        #pragma unroll
        for (int n = 0; n < NT; ++n)
            acc[m][n] = f32x4{0.f, 0.f, 0.f, 0.f};

    uint32_t bofs = (uint32_t)l4 * 8u;
    for (int kh = 0; kh < K; ++kh) {
        #pragma unroll
        for (int s = 0; s < RS; ++s) {
            bf16x8 af[NT];
            #pragma unroll
            for (int n = 0; n < NT; ++n)
                af[n] = load_frag<true>(wp + wb[n] + kh * KCIN + s * 32);
            #pragma unroll
            for (int m = 0; m < WMT; ++m) {
                bf16x8 bfr = load_frag<A16>(inb + pb[m] + bofs + s * 32);
                #pragma unroll
                for (int n = 0; n < NT; ++n)
                    acc[m][n] = mfma16(af[n], bfr, acc[m][n]);
            }
        }
        bofs += (uint32_t)(W * CIN);
    }

    float sc = 0.f;
    if constexpr (ADD_SCALAR) sc = *scal;
    bf16_t* outb = out + (size_t)b * P * COUT;
    #pragma unroll
    for (int n = 0; n < NT; ++n) {
        const int cb = cout0 + n * 16 + l4 * 4;   // 4 consecutive couts per lane
        f32x4 bv = *reinterpret_cast<const f32x4*>(bias + cb);
        #pragma unroll
        for (int m = 0; m < WMT; ++m) {
            if (pix[m] < P) {
                f32x4 v = acc[m][n];
                union { bf16x4 h; uint2 u; } st;
                #pragma unroll
                for (int r = 0; r < 4; ++r) {
                    float x = v[r] + bv[r];
                    x = x > 0.f ? x : 0.f;
                    x += sc;
                    st.h[r] = (bf16_t)x;
                }
                *reinterpret_cast<uint2*>(outb + (size_t)pix[m] * COUT + cb) = st.u;
            }
        }
    }
}

// ---------------------------------------------------------------------------
// fc2: [128,6400]x[512,6400]^T, K-split x4 into f32 partials.
// grid (nb=8, kc=4); block 256 = 4 waves as 2M x 2N; wave = 64 batch x 32 cout
// ---------------------------------------------------------------------------
__global__ __launch_bounds__(256, 2) void fc2_kernel(
    const bf16_t* __restrict__ x, const bf16_t* __restrict__ w,
    float* __restrict__ part) {
    const int nb = blockIdx.x, kc = blockIdx.y;
    const int wave = threadIdx.x >> 6, lane = threadIdx.x & 63;
    const int l15 = lane & 15, l4 = lane >> 4;
    const int wm = wave & 1, wn = wave >> 1;

    f32x4 acc[4][2];
    #pragma unroll
    for (int m = 0; m < 4; ++m)
        #pragma unroll
        for (int n = 0; n < 2; ++n) acc[m][n] = f32x4{0.f, 0.f, 0.f, 0.f};

    uint32_t xb[4], wbf[2];
    #pragma unroll
    for (int m = 0; m < 4; ++m)
        xb[m] = (uint32_t)(16 * (wm * 4 + m) + l15) * 6400u + kc * 1600u + l4 * 8u;
    #pragma unroll
    for (int n = 0; n < 2; ++n)
        wbf[n] = (uint32_t)(nb * 64 + wn * 32 + n * 16 + l15) * 6400u + kc * 1600u + l4 * 8u;

    for (int s = 0; s < 50; ++s) {
        bf16x8 af[2];
        #pragma unroll
        for (int n = 0; n < 2; ++n)
            af[n] = load_frag<true>(w + wbf[n] + s * 32);
        #pragma unroll
        for (int m = 0; m < 4; ++m) {
            bf16x8 bfr = load_frag<true>(x + xb[m] + s * 32);
            #pragma unroll
            for (int n = 0; n < 2; ++n)
                acc[m][n] = mfma16(af[n], bfr, acc[m][n]);
        }
    }
    #pragma unroll
    for (int m = 0; m < 4; ++m) {
        int bcol = 16 * (wm * 4 + m) + l15;
        #pragma unroll
        for (int n = 0; n < 2; ++n) {
            int cf = nb * 64 + wn * 32 + n * 16 + l4 * 4;
            *reinterpret_cast<f32x4*>(part + ((size_t)kc * 128 + bcol) * 512 + cf) =
                acc[m][n];
        }
    }
}

__global__ void fc2_reduce(const float* __restrict__ part,
                           const float* __restrict__ bias,
                           bf16_t* __restrict__ xo) {
    int t = blockIdx.x * 256 + threadIdx.x;
    if (t < 128 * 512) {
        int b = t >> 9, co = t & 511;
        float s = bias[co];
        #pragma unroll
        for (int kc = 0; kc < 4; ++kc) s += part[((size_t)kc * 128 + b) * 512 + co];
        xo[t] = (bf16_t)(s > 0.f ? s : 0.f);
    }
}

// fc3: [128,512]x[512,512]^T + relu -> bf16. grid(8); wave = 32 batch x 64 cout
__global__ __launch_bounds__(256, 2) void fc3_kernel(
    const bf16_t* __restrict__ x, const bf16_t* __restrict__ w,
    const float* __restrict__ bias, bf16_t* __restrict__ xo) {
    const int nb = blockIdx.x;
    const int wave = threadIdx.x >> 6, lane = threadIdx.x & 63;
    const int l15 = lane & 15, l4 = lane >> 4;

    f32x4 acc[2][4];
    #pragma unroll
    for (int m = 0; m < 2; ++m)
        #pragma unroll
        for (int n = 0; n < 4; ++n) acc[m][n] = f32x4{0.f, 0.f, 0.f, 0.f};

    uint32_t xb[2], wbf[4];
    #pragma unroll
    for (int m = 0; m < 2; ++m)
        xb[m] = (uint32_t)(16 * (wave * 2 + m) + l15) * 512u + l4 * 8u;
    #pragma unroll
    for (int n = 0; n < 4; ++n)
        wbf[n] = (uint32_t)(nb * 64 + n * 16 + l15) * 512u + l4 * 8u;

    #pragma unroll
    for (int s = 0; s < 16; ++s) {
        bf16x8 af[4];
        #pragma unroll
        for (int n = 0; n < 4; ++n) af[n] = load_frag<true>(w + wbf[n] + s * 32);
        #pragma unroll
        for (int m = 0; m < 2; ++m) {
            bf16x8 bfr = load_frag<true>(x + xb[m] + s * 32);
            #pragma unroll
            for (int n = 0; n < 4; ++n)
                acc[m][n] = mfma16(af[n], bfr, acc[m][n]);
        }
    }
    #pragma unroll
    for (int n = 0; n < 4; ++n) {
        int cf = nb * 64 + n * 16 + l4 * 4;
        f32x4 bv = *reinterpret_cast<const f32x4*>(bias + cf);
        #pragma unroll
        for (int m = 0; m < 2; ++m) {
            int brow = 16 * (wave * 2 + m) + l15;
            union { bf16x4 h; uint2 u; } st;
            #pragma unroll
            for (int r = 0; r < 4; ++r) {
                float v = acc[m][n][r] + bv[r];
                st.h[r] = (bf16_t)(v > 0.f ? v : 0.f);
            }
            *reinterpret_cast<uint2*>(xo + (size_t)brow * 512 + cf) = st.u;
        }
    }
}

// dueling head: out = adv + val - mean(adv). one wave per batch row.
__global__ void final_kernel(const bf16_t* __restrict__ x,
                             const float* __restrict__ eaw, const float* __restrict__ eab,
                             const float* __restrict__ evw, const float* __restrict__ evb,
                             float* __restrict__ out) {
    int b = blockIdx.x, lane = threadIdx.x;
    bf16x8 xv = *reinterpret_cast<const bf16x8*>(x + (size_t)b * 512 + lane * 8);
    float xs[8];
    #pragma unroll
    for (int i = 0; i < 8; ++i) xs[i] = (float)xv[i];
    float a[10];
    #pragma unroll
    for (int j = 0; j < 10; ++j) {
        const float* wr = (j < 9) ? (eaw + (size_t)j * 512) : evw;
        const f32x4* w4 = reinterpret_cast<const f32x4*>(wr + lane * 8);
        f32x4 w0 = w4[0], w1 = w4[1];
        float s = 0.f;
        #pragma unroll
        for (int i = 0; i < 4; ++i) s += xs[i] * w0[i];
        #pragma unroll
        for (int i = 0; i < 4; ++i) s += xs[4 + i] * w1[i];
        a[j] = s;
    }
    #pragma unroll
    for (int off = 1; off < 64; off <<= 1)
        #pragma unroll
        for (int j = 0; j < 10; ++j) a[j] += __shfl_xor(a[j], off);
    if (lane < 9) {
        float val  = a[9] + evb[0];
        float mean = 0.f;
        #pragma unroll
        for (int j = 0; j < 9; ++j) mean += a[j] + eab[j];
        mean *= (1.f / 9.f);
        out[b * 9 + lane] = a[lane] + eab[lane] + val - mean;
    }
}

// ---------------------------------------------------------------------------
extern "C" void kernel_launch(void* const* d_in, const int* in_sizes, int n_in,
                              void* d_out, int out_size, void* d_ws, size_t ws_size,
                              hipStream_t stream) {
    const float* state_m  = (const float*)d_in[0];
    const float* state_g  = (const float*)d_in[1];
    const float* state_v  = (const float*)d_in[2];
    const float* conv1_w  = (const float*)d_in[3];
    const float* conv1_b  = (const float*)d_in[4];
    const float* conv2_w  = (const float*)d_in[5];
    const float* conv2_b  = (const float*)d_in[6];
    const float* conv3_w  = (const float*)d_in[7];
    const float* conv3_b  = (const float*)d_in[8];
    const float* conv4_w  = (const float*)d_in[9];
    const float* conv4_b  = (const float*)d_in[10];
    const float* fc1_w    = (const float*)d_in[11];
    const float* fc1_b    = (const float*)d_in[12];
    const float* fc2_w    = (const float*)d_in[13];
    const float* fc2_b    = (const float*)d_in[14];
    const float* fc3_w    = (const float*)d_in[15];
    const float* fc3_b    = (const float*)d_in[16];
    const float* fc4_ea_w = (const float*)d_in[17];
    const float* fc4_ea_b = (const float*)d_in[18];
    const float* fc4_ev_w = (const float*)d_in[19];
    const float* fc4_ev_b = (const float*)d_in[20];

    char* ws = (char*)d_ws;
    // workspace layout (bytes)
    bf16_t* w1p    = (bf16_t*)(ws + 0);          //   262,144
    bf16_t* w2p    = (bf16_t*)(ws + 262144);     // 4,194,304
    bf16_t* w3p    = (bf16_t*)(ws + 4456448);    //   524,288
    bf16_t* w4p    = (bf16_t*)(ws + 4980736);    //   524,288
    bf16_t* fc2wp  = (bf16_t*)(ws + 5505024);    // 6,553,600
    bf16_t* fc3wp  = (bf16_t*)(ws + 12058624);   //   524,288
    float*  scal   = (float*) (ws + 12582912);
    float*  part   = (float*) (ws + 12583168);   // 1,048,576
    bf16_t* x2fc   = (bf16_t*)(ws + 13631744);   //   131,072
    bf16_t* x3fc   = (bf16_t*)(ws + 13762816);   //   131,072
    bf16_t* a0     = (bf16_t*)(ws + 14155776);   // 10,240,000 (input NHWC)
    bf16_t* x4a    = (bf16_t*)(ws + 14155776);   //  9,437,184 (reuse after conv1)
    bf16_t* x1     = (bf16_t*)(ws + 24641536);   // 39,002,112
    bf16_t* x4b    = (bf16_t*)(ws + 24641536);   //  4,734,976 (reuse after conv2)
    bf16_t* x4c    = (bf16_t*)(ws + 41418752);   //  1,638,400 (x1 + 16MB)
    bf16_t* x2     = (bf16_t*)(ws + 63963136);   // 23,658,496
    bf16_t* x3     = (bf16_t*)(ws + 87621632);   // 15,745,024
    (void)in_sizes; (void)n_in; (void)out_size; (void)ws_size;

    // weight packing + input layout conversion
    pack_w<4> <<<dim3(128),  256, 0, stream>>>(conv1_w, w1p, 32, 1024);
    pack_w<32><<<dim3(256),  256, 0, stream>>>(conv2_w, w2p, 64, 1024);
    pack_w<64><<<dim3(16),   256, 0, stream>>>(conv3_w, w3p, 64, 64);
    pack_w<64><<<dim3(16),   256, 0, stream>>>(conv4_w, w4p, 64, 64);
    pack_w<64><<<dim3(200),  256, 0, stream>>>(fc2_w, fc2wp, 512, 100);
    pack_w<1> <<<dim3(1024), 256, 0, stream>>>(fc3_w, fc3wp, 512, 512);
    pack_w<4> <<<dim3(1024), 256, 0, stream>>>(state_m, a0, 128, 10000);
    fc1_scalar<<<1, 64, 0, stream>>>(state_g, state_v, fc1_w, fc1_b, scal);

    // conv chain  <CIN,COUT,W,K,OW,NBLK,WMT,ADD_SCALAR,A16>
    conv_mfma<4, 32, 100, 32, 69, 32, 8, 0, false>
        <<<dim3(10, 1, 128), 256, 0, stream>>>(a0, w1p, conv1_b, x1, nullptr);
    conv_mfma<32, 64, 69, 32, 38, 64, 6, 0, true>
        <<<dim3(4, 1, 128), 256, 0, stream>>>(x1, w2p, conv2_b, x2, nullptr);
    conv_mfma<64, 64, 38, 8, 31, 64, 8, 1, true>
        <<<dim3(2, 1, 128), 256, 0, stream>>>(x2, w3p, conv3_b, x3, scal);
    conv_mfma<64, 64, 31, 8, 24, 64, 5, 0, true>
        <<<dim3(2, 1, 128), 256, 0, stream>>>(x3, w4p, conv4_b, x4a, nullptr);
    conv_mfma<64, 64, 24, 8, 17, 64, 3, 0, true>
        <<<dim3(2, 1, 128), 256, 0, stream>>>(x4a, w4p, conv4_b, x4b, nullptr);
    conv_mfma<64, 64, 17, 8, 10, 32, 2, 0, true>
        <<<dim3(1, 2, 128), 256, 0, stream>>>(x4b, w4p, conv4_b, x4c, nullptr);

    // FC head
    fc2_kernel<<<dim3(8, 4), 256, 0, stream>>>(x4c, fc2wp, part);
    fc2_reduce<<<dim3(256), 256, 0, stream>>>(part, fc2_b, x2fc);
    fc3_kernel<<<dim3(8), 256, 0, stream>>>(x2fc, fc3wp, fc3_b, x3fc);
    final_kernel<<<dim3(128), 64, 0, stream>>>(x3fc, fc4_ea_w, fc4_ea_b,
                                               fc4_ev_w, fc4_ev_b, (float*)d_out);
}

// Round 2
// 1904.030 us; speedup vs baseline: 1.5151x; 1.5151x over previous
//
#include <hip/hip_runtime.h>
#include <stdint.h>

// ---------------------------------------------------------------------------
// Dueling-DQN forward on MI355X. bf16 MFMA everywhere. Round 2: conv2 (77% of
// FLOPs) rewritten with rolling-row LDS staging + 32x32x16 MFMA + packed
// A-fragments; small convs get bigger grids.
// ---------------------------------------------------------------------------

using bf16_t = __bf16;
using bf16x8 = __attribute__((ext_vector_type(8))) __bf16;
using bf16x4 = __attribute__((ext_vector_type(4))) __bf16;
using f32x4  = __attribute__((ext_vector_type(4))) float;
using f32x16 = __attribute__((ext_vector_type(16))) float;

__device__ __forceinline__ f32x4 mfma16(bf16x8 a, bf16x8 b, f32x4 c) {
    return __builtin_amdgcn_mfma_f32_16x16x32_bf16(a, b, c, 0, 0, 0);
}
__device__ __forceinline__ f32x16 mfma32(bf16x8 a, bf16x8 b, f32x16 c) {
    return __builtin_amdgcn_mfma_f32_32x32x16_bf16(a, b, c, 0, 0, 0);
}

template<bool A16>
__device__ __forceinline__ bf16x8 load_frag(const bf16_t* p) {
    if constexpr (A16) {
        return *reinterpret_cast<const bf16x8*>(p);
    } else {
        union { bf16x8 v; uint64_t u[2]; } r;
        r.u[0] = *reinterpret_cast<const uint64_t*>(p);
        r.u[1] = *reinterpret_cast<const uint64_t*>(p + 4);
        return r.v;
    }
}

// ---------------------------------------------------------------------------
// Generic pack: dst[cout][khw][cin] = (bf16)src[cout][cin][khw]
// ---------------------------------------------------------------------------
template<int CIN>
__global__ void pack_w(const float* __restrict__ src, bf16_t* __restrict__ dst,
                       int COUT, int KK) {
    int total = COUT * KK;
    for (int t = blockIdx.x * blockDim.x + threadIdx.x; t < total;
         t += gridDim.x * blockDim.x) {
        int cout = t / KK;
        int khw  = t - cout * KK;
        alignas(16) bf16_t tmp[CIN];
        #pragma unroll
        for (int c = 0; c < CIN; ++c)
            tmp[c] = (bf16_t)src[((size_t)cout * CIN + c) * KK + khw];
        bf16_t* d = dst + (size_t)t * CIN;
        if constexpr (CIN == 1) {
            d[0] = tmp[0];
        } else if constexpr (CIN == 4) {
            *reinterpret_cast<uint2*>(d) = *reinterpret_cast<const uint2*>(tmp);
        } else {
            #pragma unroll
            for (int c = 0; c < CIN; c += 8)
                *reinterpret_cast<uint4*>(d + c) =
                    *reinterpret_cast<const uint4*>(tmp + c);
        }
    }
}

// ---------------------------------------------------------------------------
// conv2 A-fragment pack: frag f = (kh*64+s)*2+n holds couts n*32..n*32+31,
// k = s*16 + (lane>>5)*8 + e ; k -> (kw = k>>5, cin = k&31).
// Source OIHW (64,32,32,32). dst[f*512 + lane*8 + e], 1KB per frag.
// ---------------------------------------------------------------------------
__global__ void pack_w2A(const float* __restrict__ src, bf16_t* __restrict__ dst) {
    int t = blockIdx.x * 256 + threadIdx.x;   // 262144 threads
    int l  = t & 63;
    int f  = t >> 6;                          // 0..4095
    int n  = f & 1;
    int s  = (f >> 1) & 63;
    int kh = f >> 7;
    int cout = n * 32 + (l & 31);
    int k0   = s * 16 + (l >> 5) * 8;
    int kw   = k0 >> 5;
    int cin0 = k0 & 31;
    alignas(16) bf16_t tmp[8];
    #pragma unroll
    for (int e = 0; e < 8; ++e)
        tmp[e] = (bf16_t)src[(((size_t)cout * 32 + (cin0 + e)) * 32 + kh) * 32 + kw];
    *reinterpret_cast<uint4*>(dst + (size_t)t * 8) =
        *reinterpret_cast<const uint4*>(tmp);
}

// scalar = relu(fc1(concat(g[0],v[0]))[30])
__global__ void fc1_scalar(const float* __restrict__ g, const float* __restrict__ v,
                           const float* __restrict__ w, const float* __restrict__ b,
                           float* __restrict__ outp) {
    if (threadIdx.x == 0 && blockIdx.x == 0) {
        float s = b[30] + g[0] * w[120] + g[1] * w[121] + v[0] * w[122] + v[1] * w[123];
        *outp = s > 0.f ? s : 0.f;
    }
}

// ---------------------------------------------------------------------------
// conv2 specialized: CIN=32, W=69, K=32, OW=38, COUT=64.
// Block = 256 thr (4 waves), 384 flat output pixels (3x 32-pixel tiles/wave),
// all 64 couts. Rolling 12-slot LDS row buffer (4608B rows), 1 new row per kh.
// ---------------------------------------------------------------------------
__global__ __launch_bounds__(256, 2) void conv2_lds(
    const bf16_t* __restrict__ in,   // [128][69*69][32] NHWC
    const bf16_t* __restrict__ wA,   // packed frags
    const float* __restrict__ bias,
    bf16_t* __restrict__ out) {      // [128][38*38][64] NHWC
    constexpr int Wro   = 2208;      // input row elems (69*32)
    constexpr int ROWB  = 4608;      // LDS bytes per row slot
    constexpr int NSLOT = 12;
    constexpr int LDSB  = NSLOT * ROWB;   // 55296
    __shared__ __align__(16) char smem[LDSB];

    const int tid  = threadIdx.x;
    const int wave = tid >> 6, lane = tid & 63;
    const int l31  = lane & 31, h = lane >> 5;
    const int img  = blockIdx.z;
    const int p0   = blockIdx.x * 384;

    const bf16_t* inb = in + (size_t)img * 152352;

    const int r0 = p0 / 38;
    int plast = p0 + 383; if (plast > 1443) plast = 1443;
    const int r1 = plast / 38;

    int pix[3], ldsadr[3];
    #pragma unroll
    for (int m = 0; m < 3; ++m) {
        int p  = p0 + wave * 96 + m * 32 + l31;
        pix[m] = p;
        int pc = p < 1444 ? p : 1443;
        int oh = pc / 38;
        int ow = pc - oh * 38;
        ldsadr[m] = (oh % NSLOT) * ROWB + ow * 64 + h * 16;
    }

    // prologue: stage rows r0..r1
    for (int r = r0; r <= r1; ++r) {
        char* sl = smem + (r % NSLOT) * ROWB;
        const bf16_t* g = inb + (size_t)r * Wro;
        for (int c = tid; c < 288; c += 256) {
            bf16x8 v = *reinterpret_cast<const bf16x8*>(g + c * 8);
            *reinterpret_cast<bf16x8*>(sl + c * 16) = v;
        }
    }
    __syncthreads();

    f32x16 acc[3][2] = {};

    int wsl = (r1 + 1) % NSLOT;
    const bf16_t* gpre = inb + (size_t)(r1 + 1) * Wro;

    for (int kh = 0; kh < 32; ++kh) {
        bf16x8 st0{}, st1{};
        const bool pf = kh < 31;
        if (pf) {                                    // T14: issue early
            st0 = *reinterpret_cast<const bf16x8*>(gpre + tid * 8);
            if (tid < 32)
                st1 = *reinterpret_cast<const bf16x8*>(gpre + 2048 + tid * 8);
        }
        const bf16_t* ap = wA + (size_t)kh * 65536 + lane * 8;
        #pragma unroll 16
        for (int s = 0; s < 64; ++s) {
            bf16x8 a0 = *reinterpret_cast<const bf16x8*>(ap + s * 1024);
            bf16x8 a1 = *reinterpret_cast<const bf16x8*>(ap + s * 1024 + 512);
            #pragma unroll
            for (int m = 0; m < 3; ++m) {
                bf16x8 bfr = *reinterpret_cast<const bf16x8*>(smem + ldsadr[m] + s * 32);
                acc[m][0] = mfma32(a0, bfr, acc[m][0]);
                acc[m][1] = mfma32(a1, bfr, acc[m][1]);
            }
        }
        if (pf) {                                    // write-late
            char* wb = smem + wsl * ROWB;
            *reinterpret_cast<bf16x8*>(wb + tid * 16) = st0;
            if (tid < 32)
                *reinterpret_cast<bf16x8*>(wb + 4096 + tid * 16) = st1;
            gpre += Wro;
            wsl = (wsl + 1 == NSLOT) ? 0 : wsl + 1;
        }
        __syncthreads();
        #pragma unroll
        for (int m = 0; m < 3; ++m) {
            int a2 = ldsadr[m] + ROWB;
            ldsadr[m] = a2 >= LDSB ? a2 - LDSB : a2;
        }
    }

    bf16_t* outb = out + (size_t)img * (1444 * 64);
    #pragma unroll
    for (int m = 0; m < 3; ++m) {
        if (pix[m] < 1444) {
            #pragma unroll
            for (int n = 0; n < 2; ++n) {
                #pragma unroll
                for (int rg = 0; rg < 4; ++rg) {
                    int cb = n * 32 + rg * 8 + h * 4;
                    f32x4 bv = *reinterpret_cast<const f32x4*>(bias + cb);
                    union { bf16x4 v; uint2 u; } o;
                    #pragma unroll
                    for (int j = 0; j < 4; ++j) {
                        float x = acc[m][n][rg * 4 + j] + bv[j];
                        o.v[j] = (bf16_t)(x > 0.f ? x : 0.f);
                    }
                    *reinterpret_cast<uint2*>(outb + (size_t)pix[m] * 64 + cb) = o.u;
                }
            }
        }
    }
}

// ---------------------------------------------------------------------------
// Generic implicit-GEMM conv (16x16x32), used for conv1/conv3/conv4.
// ---------------------------------------------------------------------------
template<int CIN, int COUT, int W, int K, int OW, int NBLK, int WMT,
         int ADD_SCALAR, bool A16>
__global__ __launch_bounds__(256, 2) void conv_mfma(
    const bf16_t* __restrict__ in, const bf16_t* __restrict__ wp,
    const float* __restrict__ bias, bf16_t* __restrict__ out,
    const float* __restrict__ scal) {
    constexpr int P    = OW * OW;
    constexpr int KCIN = K * CIN;
    constexpr int KTOT = K * KCIN;
    constexpr int RS   = KCIN / 32;
    constexpr int NT   = NBLK / 16;
    constexpr int BMT  = WMT * 4;

    const int b     = blockIdx.z;
    const int cout0 = blockIdx.y * NBLK;
    const int wave  = threadIdx.x >> 6;
    const int lane  = threadIdx.x & 63;
    const int l15   = lane & 15;
    const int l4    = lane >> 4;
    const int mt0   = blockIdx.x * BMT + wave * WMT;

    const bf16_t* inb = in + (size_t)b * (W * W * CIN);

    int      pix[WMT];
    uint32_t pb[WMT];
    #pragma unroll
    for (int m = 0; m < WMT; ++m) {
        int p  = (mt0 + m) * 16 + l15;
        pix[m] = p;
        int pc = p < P ? p : P - 1;
        int oh = pc / OW;
        int ow = pc - oh * OW;
        pb[m]  = (uint32_t)(oh * W + ow) * CIN;
    }
    uint32_t wb[NT];
    #pragma unroll
    for (int n = 0; n < NT; ++n)
        wb[n] = (uint32_t)(cout0 + n * 16 + l15) * KTOT + (uint32_t)l4 * 8u;

    f32x4 acc[WMT][NT];
    #pragma unroll
    for (int m = 0; m < WMT; ++m)
        #pragma unroll
        for (int n = 0; n < NT; ++n)
            acc[m][n] = f32x4{0.f, 0.f, 0.f, 0.f};

    uint32_t bofs = (uint32_t)l4 * 8u;
    for (int kh = 0; kh < K; ++kh) {
        #pragma unroll
        for (int s = 0; s < RS; ++s) {
            bf16x8 af[NT];
            #pragma unroll
            for (int n = 0; n < NT; ++n)
                af[n] = load_frag<true>(wp + wb[n] + kh * KCIN + s * 32);
            #pragma unroll
            for (int m = 0; m < WMT; ++m) {
                bf16x8 bfr = load_frag<A16>(inb + pb[m] + bofs + s * 32);
                #pragma unroll
                for (int n = 0; n < NT; ++n)
                    acc[m][n] = mfma16(af[n], bfr, acc[m][n]);
            }
        }
        bofs += (uint32_t)(W * CIN);
    }

    float sc = 0.f;
    if constexpr (ADD_SCALAR) sc = *scal;
    bf16_t* outb = out + (size_t)b * P * COUT;
    #pragma unroll
    for (int n = 0; n < NT; ++n) {
        const int cb = cout0 + n * 16 + l4 * 4;
        f32x4 bv = *reinterpret_cast<const f32x4*>(bias + cb);
        #pragma unroll
        for (int m = 0; m < WMT; ++m) {
            if (pix[m] < P) {
                f32x4 v = acc[m][n];
                union { bf16x4 h; uint2 u; } st;
                #pragma unroll
                for (int r = 0; r < 4; ++r) {
                    float x = v[r] + bv[r];
                    x = x > 0.f ? x : 0.f;
                    x += sc;
                    st.h[r] = (bf16_t)x;
                }
                *reinterpret_cast<uint2*>(outb + (size_t)pix[m] * COUT + cb) = st.u;
            }
        }
    }
}

// ---------------------------------------------------------------------------
// fc2: [128,6400]x[512,6400]^T, K-split x4 into f32 partials.
// ---------------------------------------------------------------------------
__global__ __launch_bounds__(256, 2) void fc2_kernel(
    const bf16_t* __restrict__ x, const bf16_t* __restrict__ w,
    float* __restrict__ part) {
    const int nb = blockIdx.x, kc = blockIdx.y;
    const int wave = threadIdx.x >> 6, lane = threadIdx.x & 63;
    const int l15 = lane & 15, l4 = lane >> 4;
    const int wm = wave & 1, wn = wave >> 1;

    f32x4 acc[4][2];
    #pragma unroll
    for (int m = 0; m < 4; ++m)
        #pragma unroll
        for (int n = 0; n < 2; ++n) acc[m][n] = f32x4{0.f, 0.f, 0.f, 0.f};

    uint32_t xb[4], wbf[2];
    #pragma unroll
    for (int m = 0; m < 4; ++m)
        xb[m] = (uint32_t)(16 * (wm * 4 + m) + l15) * 6400u + kc * 1600u + l4 * 8u;
    #pragma unroll
    for (int n = 0; n < 2; ++n)
        wbf[n] = (uint32_t)(nb * 64 + wn * 32 + n * 16 + l15) * 6400u + kc * 1600u + l4 * 8u;

    for (int s = 0; s < 50; ++s) {
        bf16x8 af[2];
        #pragma unroll
        for (int n = 0; n < 2; ++n)
            af[n] = load_frag<true>(w + wbf[n] + s * 32);
        #pragma unroll
        for (int m = 0; m < 4; ++m) {
            bf16x8 bfr = load_frag<true>(x + xb[m] + s * 32);
            #pragma unroll
            for (int n = 0; n < 2; ++n)
                acc[m][n] = mfma16(af[n], bfr, acc[m][n]);
        }
    }
    #pragma unroll
    for (int m = 0; m < 4; ++m) {
        int bcol = 16 * (wm * 4 + m) + l15;
        #pragma unroll
        for (int n = 0; n < 2; ++n) {
            int cf = nb * 64 + wn * 32 + n * 16 + l4 * 4;
            *reinterpret_cast<f32x4*>(part + ((size_t)kc * 128 + bcol) * 512 + cf) =
                acc[m][n];
        }
    }
}

__global__ void fc2_reduce(const float* __restrict__ part,
                           const float* __restrict__ bias,
                           bf16_t* __restrict__ xo) {
    int t = blockIdx.x * 256 + threadIdx.x;
    if (t < 128 * 512) {
        int b = t >> 9, co = t & 511;
        float s = bias[co];
        #pragma unroll
        for (int kc = 0; kc < 4; ++kc) s += part[((size_t)kc * 128 + b) * 512 + co];
        xo[t] = (bf16_t)(s > 0.f ? s : 0.f);
    }
}

__global__ __launch_bounds__(256, 2) void fc3_kernel(
    const bf16_t* __restrict__ x, const bf16_t* __restrict__ w,
    const float* __restrict__ bias, bf16_t* __restrict__ xo) {
    const int nb = blockIdx.x;
    const int wave = threadIdx.x >> 6, lane = threadIdx.x & 63;
    const int l15 = lane & 15, l4 = lane >> 4;

    f32x4 acc[2][4];
    #pragma unroll
    for (int m = 0; m < 2; ++m)
        #pragma unroll
        for (int n = 0; n < 4; ++n) acc[m][n] = f32x4{0.f, 0.f, 0.f, 0.f};

    uint32_t xb[2], wbf[4];
    #pragma unroll
    for (int m = 0; m < 2; ++m)
        xb[m] = (uint32_t)(16 * (wave * 2 + m) + l15) * 512u + l4 * 8u;
    #pragma unroll
    for (int n = 0; n < 4; ++n)
        wbf[n] = (uint32_t)(nb * 64 + n * 16 + l15) * 512u + l4 * 8u;

    #pragma unroll
    for (int s = 0; s < 16; ++s) {
        bf16x8 af[4];
        #pragma unroll
        for (int n = 0; n < 4; ++n) af[n] = load_frag<true>(w + wbf[n] + s * 32);
        #pragma unroll
        for (int m = 0; m < 2; ++m) {
            bf16x8 bfr = load_frag<true>(x + xb[m] + s * 32);
            #pragma unroll
            for (int n = 0; n < 4; ++n)
                acc[m][n] = mfma16(af[n], bfr, acc[m][n]);
        }
    }
    #pragma unroll
    for (int n = 0; n < 4; ++n) {
        int cf = nb * 64 + n * 16 + l4 * 4;
        f32x4 bv = *reinterpret_cast<const f32x4*>(bias + cf);
        #pragma unroll
        for (int m = 0; m < 2; ++m) {
            int brow = 16 * (wave * 2 + m) + l15;
            union { bf16x4 h; uint2 u; } st;
            #pragma unroll
            for (int r = 0; r < 4; ++r) {
                float v = acc[m][n][r] + bv[r];
                st.h[r] = (bf16_t)(v > 0.f ? v : 0.f);
            }
            *reinterpret_cast<uint2*>(xo + (size_t)brow * 512 + cf) = st.u;
        }
    }
}

__global__ void final_kernel(const bf16_t* __restrict__ x,
                             const float* __restrict__ eaw, const float* __restrict__ eab,
                             const float* __restrict__ evw, const float* __restrict__ evb,
                             float* __restrict__ out) {
    int b = blockIdx.x, lane = threadIdx.x;
    bf16x8 xv = *reinterpret_cast<const bf16x8*>(x + (size_t)b * 512 + lane * 8);
    float xs[8];
    #pragma unroll
    for (int i = 0; i < 8; ++i) xs[i] = (float)xv[i];
    float a[10];
    #pragma unroll
    for (int j = 0; j < 10; ++j) {
        const float* wr = (j < 9) ? (eaw + (size_t)j * 512) : evw;
        const f32x4* w4 = reinterpret_cast<const f32x4*>(wr + lane * 8);
        f32x4 w0 = w4[0], w1 = w4[1];
        float s = 0.f;
        #pragma unroll
        for (int i = 0; i < 4; ++i) s += xs[i] * w0[i];
        #pragma unroll
        for (int i = 0; i < 4; ++i) s += xs[4 + i] * w1[i];
        a[j] = s;
    }
    #pragma unroll
    for (int off = 1; off < 64; off <<= 1)
        #pragma unroll
        for (int j = 0; j < 10; ++j) a[j] += __shfl_xor(a[j], off);
    if (lane < 9) {
        float val  = a[9] + evb[0];
        float mean = 0.f;
        #pragma unroll
        for (int j = 0; j < 9; ++j) mean += a[j] + eab[j];
        mean *= (1.f / 9.f);
        out[b * 9 + lane] = a[lane] + eab[lane] + val - mean;
    }
}

// ---------------------------------------------------------------------------
extern "C" void kernel_launch(void* const* d_in, const int* in_sizes, int n_in,
                              void* d_out, int out_size, void* d_ws, size_t ws_size,
                              hipStream_t stream) {
    const float* state_m  = (const float*)d_in[0];
    const float* state_g  = (const float*)d_in[1];
    const float* state_v  = (const float*)d_in[2];
    const float* conv1_w  = (const float*)d_in[3];
    const float* conv1_b  = (const float*)d_in[4];
    const float* conv2_w  = (const float*)d_in[5];
    const float* conv2_b  = (const float*)d_in[6];
    const float* conv3_w  = (const float*)d_in[7];
    const float* conv3_b  = (const float*)d_in[8];
    const float* conv4_w  = (const float*)d_in[9];
    const float* conv4_b  = (const float*)d_in[10];
    const float* fc1_w    = (const float*)d_in[11];
    const float* fc1_b    = (const float*)d_in[12];
    const float* fc2_w    = (const float*)d_in[13];
    const float* fc2_b    = (const float*)d_in[14];
    const float* fc3_w    = (const float*)d_in[15];
    const float* fc3_b    = (const float*)d_in[16];
    const float* fc4_ea_w = (const float*)d_in[17];
    const float* fc4_ea_b = (const float*)d_in[18];
    const float* fc4_ev_w = (const float*)d_in[19];
    const float* fc4_ev_b = (const float*)d_in[20];

    char* ws = (char*)d_ws;
    bf16_t* w1p    = (bf16_t*)(ws + 0);          //   262,144
    bf16_t* w2A    = (bf16_t*)(ws + 262144);     // 4,194,304 (conv2 packed frags)
    bf16_t* w3p    = (bf16_t*)(ws + 4456448);    //   524,288
    bf16_t* w4p    = (bf16_t*)(ws + 4980736);    //   524,288
    bf16_t* fc2wp  = (bf16_t*)(ws + 5505024);    // 6,553,600
    bf16_t* fc3wp  = (bf16_t*)(ws + 12058624);   //   524,288
    float*  scal   = (float*) (ws + 12582912);
    float*  part   = (float*) (ws + 12583168);   // 1,048,576
    bf16_t* x2fc   = (bf16_t*)(ws + 13631744);   //   131,072
    bf16_t* x3fc   = (bf16_t*)(ws + 13762816);   //   131,072
    bf16_t* a0     = (bf16_t*)(ws + 14155776);   // input NHWC
    bf16_t* x4a    = (bf16_t*)(ws + 14155776);   // reuse after conv1
    bf16_t* x1     = (bf16_t*)(ws + 24641536);
    bf16_t* x4b    = (bf16_t*)(ws + 24641536);   // reuse after conv2
    bf16_t* x4c    = (bf16_t*)(ws + 41418752);
    bf16_t* x2     = (bf16_t*)(ws + 63963136);
    bf16_t* x3     = (bf16_t*)(ws + 87621632);
    (void)in_sizes; (void)n_in; (void)out_size; (void)ws_size;

    pack_w<4> <<<dim3(128),  256, 0, stream>>>(conv1_w, w1p, 32, 1024);
    pack_w2A  <<<dim3(1024), 256, 0, stream>>>(conv2_w, w2A);
    pack_w<64><<<dim3(16),   256, 0, stream>>>(conv3_w, w3p, 64, 64);
    pack_w<64><<<dim3(16),   256, 0, stream>>>(conv4_w, w4p, 64, 64);
    pack_w<64><<<dim3(200),  256, 0, stream>>>(fc2_w, fc2wp, 512, 100);
    pack_w<1> <<<dim3(1024), 256, 0, stream>>>(fc3_w, fc3wp, 512, 512);
    pack_w<4> <<<dim3(1024), 256, 0, stream>>>(state_m, a0, 128, 10000);
    fc1_scalar<<<1, 64, 0, stream>>>(state_g, state_v, fc1_w, fc1_b, scal);

    // conv chain
    conv_mfma<4, 32, 100, 32, 69, 32, 8, 0, false>
        <<<dim3(10, 1, 128), 256, 0, stream>>>(a0, w1p, conv1_b, x1, nullptr);
    conv2_lds<<<dim3(4, 1, 128), 256, 0, stream>>>(x1, w2A, conv2_b, x2);
    conv_mfma<64, 64, 38, 8, 31, 64, 4, 1, true>
        <<<dim3(4, 1, 128), 256, 0, stream>>>(x2, w3p, conv3_b, x3, scal);
    conv_mfma<64, 64, 31, 8, 24, 64, 3, 0, true>
        <<<dim3(3, 1, 128), 256, 0, stream>>>(x3, w4p, conv4_b, x4a, nullptr);
    conv_mfma<64, 64, 24, 8, 17, 64, 2, 0, true>
        <<<dim3(3, 1, 128), 256, 0, stream>>>(x4a, w4p, conv4_b, x4b, nullptr);
    conv_mfma<64, 64, 17, 8, 10, 32, 1, 0, true>
        <<<dim3(2, 2, 128), 256, 0, stream>>>(x4b, w4p, conv4_b, x4c, nullptr);

    // FC head
    fc2_kernel<<<dim3(8, 4), 256, 0, stream>>>(x4c, fc2wp, part);
    fc2_reduce<<<dim3(256), 256, 0, stream>>>(part, fc2_b, x2fc);
    fc3_kernel<<<dim3(8), 256, 0, stream>>>(x2fc, fc3wp, fc3_b, x3fc);
    final_kernel<<<dim3(128), 64, 0, stream>>>(x3fc, fc4_ea_w, fc4_ea_b,
                                               fc4_ev_w, fc4_ev_b, (float*)d_out);
}

// Round 4
// 1835.394 us; speedup vs baseline: 1.5717x; 1.0374x over previous
//
#include <hip/hip_runtime.h>
#include <stdint.h>

// ---------------------------------------------------------------------------
// Dueling-DQN forward on MI355X. Round 4: identical kernels to round 3
// (rolling-row LDS conv template, 32x32x16 MFMA, XOR bank-swizzle), with the
// workspace overlap fixed: ALL weight buffers live below the activation
// region; activation reuse only where producer strictly follows consumer.
// ---------------------------------------------------------------------------

using bf16_t = __bf16;
using bf16x8 = __attribute__((ext_vector_type(8))) __bf16;
using bf16x4 = __attribute__((ext_vector_type(4))) __bf16;
using f32x4  = __attribute__((ext_vector_type(4))) float;
using f32x16 = __attribute__((ext_vector_type(16))) float;

__device__ __forceinline__ f32x4 mfma16(bf16x8 a, bf16x8 b, f32x4 c) {
    return __builtin_amdgcn_mfma_f32_16x16x32_bf16(a, b, c, 0, 0, 0);
}
__device__ __forceinline__ f32x16 mfma32(bf16x8 a, bf16x8 b, f32x16 c) {
    return __builtin_amdgcn_mfma_f32_32x32x16_bf16(a, b, c, 0, 0, 0);
}

// bank swizzle on absolute LDS byte address (bits >=4 only -> 16B units kept)
template<int PIXB>
__device__ __forceinline__ int swz(int a) {
    if constexpr (PIXB == 64)       return a ^ (((a >> 7) & 3) << 4);
    else if constexpr (PIXB == 128) return a ^ (((a >> 7) & 7) << 4);
    else                            return a;   // 8B pixels: naturally ~2-way
}

template<bool A16>
__device__ __forceinline__ bf16x8 load_frag(const bf16_t* p) {
    if constexpr (A16) {
        return *reinterpret_cast<const bf16x8*>(p);
    } else {
        union { bf16x8 v; uint64_t u[2]; } r;
        r.u[0] = *reinterpret_cast<const uint64_t*>(p);
        r.u[1] = *reinterpret_cast<const uint64_t*>(p + 4);
        return r.v;
    }
}

// ---------------------------------------------------------------------------
// Generic pack: dst[cout][khw][cin] = (bf16)src[cout][cin][khw]
// ---------------------------------------------------------------------------
template<int CIN>
__global__ void pack_w(const float* __restrict__ src, bf16_t* __restrict__ dst,
                       int COUT, int KK) {
    int total = COUT * KK;
    for (int t = blockIdx.x * blockDim.x + threadIdx.x; t < total;
         t += gridDim.x * blockDim.x) {
        int cout = t / KK;
        int khw  = t - cout * KK;
        alignas(16) bf16_t tmp[CIN];
        #pragma unroll
        for (int c = 0; c < CIN; ++c)
            tmp[c] = (bf16_t)src[((size_t)cout * CIN + c) * KK + khw];
        bf16_t* d = dst + (size_t)t * CIN;
        if constexpr (CIN == 1) {
            d[0] = tmp[0];
        } else if constexpr (CIN == 4) {
            *reinterpret_cast<uint2*>(d) = *reinterpret_cast<const uint2*>(tmp);
        } else {
            #pragma unroll
            for (int c = 0; c < CIN; c += 8)
                *reinterpret_cast<uint4*>(d + c) =
                    *reinterpret_cast<const uint4*>(tmp + c);
        }
    }
}

// ---------------------------------------------------------------------------
// A-fragment pack for 32x32x16 MFMA conv: frag f = (kh*S + s)*NT + n holds
// couts n*32+(l&31); k = s*16 + (l>>5)*8 + e; k -> (kw = k/CIN, cin = k%CIN).
// Source OIHW [COUT][CIN][K][K]. dst[f*512 + lane*8 + e], 1KB per frag.
// ---------------------------------------------------------------------------
template<int CIN, int COUT, int K>
__global__ void pack_wA(const float* __restrict__ src, bf16_t* __restrict__ dst) {
    constexpr int S  = K * CIN / 16;
    constexpr int NT = COUT / 32;
    int t = blockIdx.x * 256 + threadIdx.x;
    int l  = t & 63;
    int f  = t >> 6;
    int n  = f % NT;
    int fs = f / NT;
    int s  = fs % S;
    int kh = fs / S;
    if (kh >= K) return;
    int cout = n * 32 + (l & 31);
    int k0   = s * 16 + (l >> 5) * 8;
    alignas(16) bf16_t tmp[8];
    #pragma unroll
    for (int e = 0; e < 8; ++e) {
        int k   = k0 + e;
        int kw  = k / CIN;
        int cin = k % CIN;
        tmp[e] = (bf16_t)src[(((size_t)cout * CIN + cin) * K + kh) * K + kw];
    }
    *reinterpret_cast<uint4*>(dst + (size_t)t * 8) =
        *reinterpret_cast<const uint4*>(tmp);
}

// scalar = relu(fc1(concat(g[0],v[0]))[30])
__global__ void fc1_scalar(const float* __restrict__ g, const float* __restrict__ v,
                           const float* __restrict__ w, const float* __restrict__ b,
                           float* __restrict__ outp) {
    if (threadIdx.x == 0 && blockIdx.x == 0) {
        float s = b[30] + g[0] * w[120] + g[1] * w[121] + v[0] * w[122] + v[1] * w[123];
        *outp = s > 0.f ? s : 0.f;
    }
}

// ---------------------------------------------------------------------------
// Rolling-row LDS implicit-GEMM conv, 32x32x16 MFMA.
//   in : [B][W][W][CIN] NHWC bf16, wA: packed frags, out NHWC + relu(+scalar)
// Block = 4 waves x WMT 32-px m-tiles; circular NSLOT-row LDS buffer;
// one row prefetched per kh (issue-early / write-late).
// ---------------------------------------------------------------------------
template<int CIN, int COUT, int W, int K, int OW, int WMT, int NSLOT,
         int ADD_SCALAR>
__global__ __launch_bounds__(256, 2) void conv_rr(
    const bf16_t* __restrict__ in, const bf16_t* __restrict__ wA,
    const float* __restrict__ bias, bf16_t* __restrict__ out,
    const float* __restrict__ scal) {
    constexpr int P    = OW * OW;
    constexpr int PIXB = CIN * 2;
    constexpr int ROWB = W * PIXB;
    constexpr int LDSB = NSLOT * ROWB;
    constexpr int S    = K * CIN / 16;
    constexpr int NT   = COUT / 32;
    constexpr int BPX  = WMT * 32 * 4;
    constexpr int CH   = ROWB / 16;          // 16B chunks per row
    constexpr int NLD  = (CH + 255) / 256;
    __shared__ __align__(16) char smem[LDSB];

    const int tid  = threadIdx.x;
    const int wave = tid >> 6, lane = tid & 63;
    const int l31  = lane & 31, h = lane >> 5;
    const int img  = blockIdx.z;
    const int p0   = blockIdx.x * BPX;

    const char* inb = (const char*)(in + (size_t)img * ((size_t)W * W * CIN));

    const int r0 = p0 / OW;
    int plast = p0 + BPX - 1; if (plast > P - 1) plast = P - 1;
    const int r1 = plast / OW;

    int pix[WMT], ldsadr[WMT];
    #pragma unroll
    for (int m = 0; m < WMT; ++m) {
        int p  = p0 + (wave * WMT + m) * 32 + l31;
        pix[m] = p;
        int pc = p < P ? p : P - 1;
        int oh = pc / OW;
        int ow = pc - oh * OW;
        ldsadr[m] = (oh % NSLOT) * ROWB + ow * PIXB + h * 16;
    }

    // prologue: stage rows r0..r1
    for (int r = r0; r <= r1; ++r) {
        const char* g = inb + (size_t)r * ROWB;
        int base = (r % NSLOT) * ROWB;
        for (int c = tid; c < CH; c += 256) {
            bf16x8 v = *reinterpret_cast<const bf16x8*>(g + c * 16);
            *reinterpret_cast<bf16x8*>(smem + swz<PIXB>(base + c * 16)) = v;
        }
    }
    __syncthreads();

    f32x16 acc[WMT][NT] = {};

    int wsl = (r1 + 1) % NSLOT;
    const char* gpre = inb + (size_t)(r1 + 1) * ROWB;
    const bf16_t* wl = wA + lane * 8;

    for (int kh = 0; kh < K; ++kh) {
        bf16x8 stv[NLD];
        const bool pf = kh < K - 1;
        if (pf) {                                    // T14: issue early
            #pragma unroll
            for (int i = 0; i < NLD; ++i) {
                int c = i * 256 + tid;
                if (c < CH) stv[i] = *reinterpret_cast<const bf16x8*>(gpre + c * 16);
            }
        }
        const bf16_t* ap = wl + (size_t)kh * (S * NT * 512);
        #pragma unroll 8
        for (int s = 0; s < S; ++s) {
            bf16x8 af[NT];
            #pragma unroll
            for (int n = 0; n < NT; ++n)
                af[n] = *reinterpret_cast<const bf16x8*>(ap + (s * NT + n) * 512);
            #pragma unroll
            for (int m = 0; m < WMT; ++m) {
                int a = ldsadr[m] + s * 32;
                bf16x8 bfr = *reinterpret_cast<const bf16x8*>(smem + swz<PIXB>(a));
                #pragma unroll
                for (int n = 0; n < NT; ++n)
                    acc[m][n] = mfma32(af[n], bfr, acc[m][n]);
            }
        }
        if (pf) {                                    // write-late
            int wb0 = wsl * ROWB;
            #pragma unroll
            for (int i = 0; i < NLD; ++i) {
                int c = i * 256 + tid;
                if (c < CH)
                    *reinterpret_cast<bf16x8*>(smem + swz<PIXB>(wb0 + c * 16)) = stv[i];
            }
            gpre += ROWB;
            wsl = (wsl + 1 == NSLOT) ? 0 : wsl + 1;
        }
        __syncthreads();
        #pragma unroll
        for (int m = 0; m < WMT; ++m) {
            int a2 = ldsadr[m] + ROWB;
            ldsadr[m] = a2 >= LDSB ? a2 - LDSB : a2;
        }
    }

    float sc = 0.f;
    if constexpr (ADD_SCALAR) sc = *scal;
    bf16_t* outb = out + (size_t)img * ((size_t)P * COUT);
    #pragma unroll
    for (int m = 0; m < WMT; ++m) {
        if (pix[m] < P) {
            #pragma unroll
            for (int n = 0; n < NT; ++n) {
                #pragma unroll
                for (int rg = 0; rg < 4; ++rg) {
                    int cb = n * 32 + rg * 8 + h * 4;
                    f32x4 bv = *reinterpret_cast<const f32x4*>(bias + cb);
                    union { bf16x4 v; uint2 u; } o;
                    #pragma unroll
                    for (int j = 0; j < 4; ++j) {
                        float x = acc[m][n][rg * 4 + j] + bv[j];
                        x = x > 0.f ? x : 0.f;
                        x += sc;
                        o.v[j] = (bf16_t)x;
                    }
                    *reinterpret_cast<uint2*>(outb + (size_t)pix[m] * COUT + cb) = o.u;
                }
            }
        }
    }
}

// ---------------------------------------------------------------------------
// Generic implicit-GEMM conv (16x16x32) via global loads — used for conv4c.
// ---------------------------------------------------------------------------
template<int CIN, int COUT, int W, int K, int OW, int NBLK, int WMT,
         int ADD_SCALAR, bool A16>
__global__ __launch_bounds__(256, 2) void conv_mfma(
    const bf16_t* __restrict__ in, const bf16_t* __restrict__ wp,
    const float* __restrict__ bias, bf16_t* __restrict__ out,
    const float* __restrict__ scal) {
    constexpr int P    = OW * OW;
    constexpr int KCIN = K * CIN;
    constexpr int KTOT = K * KCIN;
    constexpr int RS   = KCIN / 32;
    constexpr int NT   = NBLK / 16;
    constexpr int BMT  = WMT * 4;

    const int b     = blockIdx.z;
    const int cout0 = blockIdx.y * NBLK;
    const int wave  = threadIdx.x >> 6;
    const int lane  = threadIdx.x & 63;
    const int l15   = lane & 15;
    const int l4    = lane >> 4;
    const int mt0   = blockIdx.x * BMT + wave * WMT;

    const bf16_t* inb = in + (size_t)b * (W * W * CIN);

    int      pix[WMT];
    uint32_t pb[WMT];
    #pragma unroll
    for (int m = 0; m < WMT; ++m) {
        int p  = (mt0 + m) * 16 + l15;
        pix[m] = p;
        int pc = p < P ? p : P - 1;
        int oh = pc / OW;
        int ow = pc - oh * OW;
        pb[m]  = (uint32_t)(oh * W + ow) * CIN;
    }
    uint32_t wb[NT];
    #pragma unroll
    for (int n = 0; n < NT; ++n)
        wb[n] = (uint32_t)(cout0 + n * 16 + l15) * KTOT + (uint32_t)l4 * 8u;

    f32x4 acc[WMT][NT];
    #pragma unroll
    for (int m = 0; m < WMT; ++m)
        #pragma unroll
        for (int n = 0; n < NT; ++n)
            acc[m][n] = f32x4{0.f, 0.f, 0.f, 0.f};

    uint32_t bofs = (uint32_t)l4 * 8u;
    for (int kh = 0; kh < K; ++kh) {
        #pragma unroll
        for (int s = 0; s < RS; ++s) {
            bf16x8 af[NT];
            #pragma unroll
            for (int n = 0; n < NT; ++n)
                af[n] = load_frag<true>(wp + wb[n] + kh * KCIN + s * 32);
            #pragma unroll
            for (int m = 0; m < WMT; ++m) {
                bf16x8 bfr = load_frag<A16>(inb + pb[m] + bofs + s * 32);
                #pragma unroll
                for (int n = 0; n < NT; ++n)
                    acc[m][n] = mfma16(af[n], bfr, acc[m][n]);
            }
        }
        bofs += (uint32_t)(W * CIN);
    }

    float sc = 0.f;
    if constexpr (ADD_SCALAR) sc = *scal;
    bf16_t* outb = out + (size_t)b * P * COUT;
    #pragma unroll
    for (int n = 0; n < NT; ++n) {
        const int cb = cout0 + n * 16 + l4 * 4;
        f32x4 bv = *reinterpret_cast<const f32x4*>(bias + cb);
        #pragma unroll
        for (int m = 0; m < WMT; ++m) {
            if (pix[m] < P) {
                f32x4 v = acc[m][n];
                union { bf16x4 h; uint2 u; } st;
                #pragma unroll
                for (int r = 0; r < 4; ++r) {
                    float x = v[r] + bv[r];
                    x = x > 0.f ? x : 0.f;
                    x += sc;
                    st.h[r] = (bf16_t)x;
                }
                *reinterpret_cast<uint2*>(outb + (size_t)pix[m] * COUT + cb) = st.u;
            }
        }
    }
}

// ---------------------------------------------------------------------------
// fc2: [128,6400]x[512,6400]^T, K-split x4 into f32 partials.
// ---------------------------------------------------------------------------
__global__ __launch_bounds__(256, 2) void fc2_kernel(
    const bf16_t* __restrict__ x, const bf16_t* __restrict__ w,
    float* __restrict__ part) {
    const int nb = blockIdx.x, kc = blockIdx.y;
    const int wave = threadIdx.x >> 6, lane = threadIdx.x & 63;
    const int l15 = lane & 15, l4 = lane >> 4;
    const int wm = wave & 1, wn = wave >> 1;

    f32x4 acc[4][2];
    #pragma unroll
    for (int m = 0; m < 4; ++m)
        #pragma unroll
        for (int n = 0; n < 2; ++n) acc[m][n] = f32x4{0.f, 0.f, 0.f, 0.f};

    uint32_t xb[4], wbf[2];
    #pragma unroll
    for (int m = 0; m < 4; ++m)
        xb[m] = (uint32_t)(16 * (wm * 4 + m) + l15) * 6400u + kc * 1600u + l4 * 8u;
    #pragma unroll
    for (int n = 0; n < 2; ++n)
        wbf[n] = (uint32_t)(nb * 64 + wn * 32 + n * 16 + l15) * 6400u + kc * 1600u + l4 * 8u;

    for (int s = 0; s < 50; ++s) {
        bf16x8 af[2];
        #pragma unroll
        for (int n = 0; n < 2; ++n)
            af[n] = load_frag<true>(w + wbf[n] + s * 32);
        #pragma unroll
        for (int m = 0; m < 4; ++m) {
            bf16x8 bfr = load_frag<true>(x + xb[m] + s * 32);
            #pragma unroll
            for (int n = 0; n < 2; ++n)
                acc[m][n] = mfma16(af[n], bfr, acc[m][n]);
        }
    }
    #pragma unroll
    for (int m = 0; m < 4; ++m) {
        int bcol = 16 * (wm * 4 + m) + l15;
        #pragma unroll
        for (int n = 0; n < 2; ++n) {
            int cf = nb * 64 + wn * 32 + n * 16 + l4 * 4;
            *reinterpret_cast<f32x4*>(part + ((size_t)kc * 128 + bcol) * 512 + cf) =
                acc[m][n];
        }
    }
}

__global__ void fc2_reduce(const float* __restrict__ part,
                           const float* __restrict__ bias,
                           bf16_t* __restrict__ xo) {
    int t = blockIdx.x * 256 + threadIdx.x;
    if (t < 128 * 512) {
        int b = t >> 9, co = t & 511;
        float s = bias[co];
        #pragma unroll
        for (int kc = 0; kc < 4; ++kc) s += part[((size_t)kc * 128 + b) * 512 + co];
        xo[t] = (bf16_t)(s > 0.f ? s : 0.f);
    }
}

__global__ __launch_bounds__(256, 2) void fc3_kernel(
    const bf16_t* __restrict__ x, const bf16_t* __restrict__ w,
    const float* __restrict__ bias, bf16_t* __restrict__ xo) {
    const int nb = blockIdx.x;
    const int wave = threadIdx.x >> 6, lane = threadIdx.x & 63;
    const int l15 = lane & 15, l4 = lane >> 4;

    f32x4 acc[2][4];
    #pragma unroll
    for (int m = 0; m < 2; ++m)
        #pragma unroll
        for (int n = 0; n < 4; ++n) acc[m][n] = f32x4{0.f, 0.f, 0.f, 0.f};

    uint32_t xb[2], wbf[4];
    #pragma unroll
    for (int m = 0; m < 2; ++m)
        xb[m] = (uint32_t)(16 * (wave * 2 + m) + l15) * 512u + l4 * 8u;
    #pragma unroll
    for (int n = 0; n < 4; ++n)
        wbf[n] = (uint32_t)(nb * 64 + n * 16 + l15) * 512u + l4 * 8u;

    #pragma unroll
    for (int s = 0; s < 16; ++s) {
        bf16x8 af[4];
        #pragma unroll
        for (int n = 0; n < 4; ++n) af[n] = load_frag<true>(w + wbf[n] + s * 32);
        #pragma unroll
        for (int m = 0; m < 2; ++m) {
            bf16x8 bfr = load_frag<true>(x + xb[m] + s * 32);
            #pragma unroll
            for (int n = 0; n < 4; ++n)
                acc[m][n] = mfma16(af[n], bfr, acc[m][n]);
        }
    }
    #pragma unroll
    for (int n = 0; n < 4; ++n) {
        int cf = nb * 64 + n * 16 + l4 * 4;
        f32x4 bv = *reinterpret_cast<const f32x4*>(bias + cf);
        #pragma unroll
        for (int m = 0; m < 2; ++m) {
            int brow = 16 * (wave * 2 + m) + l15;
            union { bf16x4 h; uint2 u; } st;
            #pragma unroll
            for (int r = 0; r < 4; ++r) {
                float v = acc[m][n][r] + bv[r];
                st.h[r] = (bf16_t)(v > 0.f ? v : 0.f);
            }
            *reinterpret_cast<uint2*>(xo + (size_t)brow * 512 + cf) = st.u;
        }
    }
}

__global__ void final_kernel(const bf16_t* __restrict__ x,
                             const float* __restrict__ eaw, const float* __restrict__ eab,
                             const float* __restrict__ evw, const float* __restrict__ evb,
                             float* __restrict__ out) {
    int b = blockIdx.x, lane = threadIdx.x;
    bf16x8 xv = *reinterpret_cast<const bf16x8*>(x + (size_t)b * 512 + lane * 8);
    float xs[8];
    #pragma unroll
    for (int i = 0; i < 8; ++i) xs[i] = (float)xv[i];
    float a[10];
    #pragma unroll
    for (int j = 0; j < 10; ++j) {
        const float* wr = (j < 9) ? (eaw + (size_t)j * 512) : evw;
        const f32x4* w4 = reinterpret_cast<const f32x4*>(wr + lane * 8);
        f32x4 w0 = w4[0], w1 = w4[1];
        float s = 0.f;
        #pragma unroll
        for (int i = 0; i < 4; ++i) s += xs[i] * w0[i];
        #pragma unroll
        for (int i = 0; i < 4; ++i) s += xs[4 + i] * w1[i];
        a[j] = s;
    }
    #pragma unroll
    for (int off = 1; off < 64; off <<= 1)
        #pragma unroll
        for (int j = 0; j < 10; ++j) a[j] += __shfl_xor(a[j], off);
    if (lane < 9) {
        float val  = a[9] + evb[0];
        float mean = 0.f;
        #pragma unroll
        for (int j = 0; j < 9; ++j) mean += a[j] + eab[j];
        mean *= (1.f / 9.f);
        out[b * 9 + lane] = a[lane] + eab[lane] + val - mean;
    }
}

// ---------------------------------------------------------------------------
extern "C" void kernel_launch(void* const* d_in, const int* in_sizes, int n_in,
                              void* d_out, int out_size, void* d_ws, size_t ws_size,
                              hipStream_t stream) {
    const float* state_m  = (const float*)d_in[0];
    const float* state_g  = (const float*)d_in[1];
    const float* state_v  = (const float*)d_in[2];
    const float* conv1_w  = (const float*)d_in[3];
    const float* conv1_b  = (const float*)d_in[4];
    const float* conv2_w  = (const float*)d_in[5];
    const float* conv2_b  = (const float*)d_in[6];
    const float* conv3_w  = (const float*)d_in[7];
    const float* conv3_b  = (const float*)d_in[8];
    const float* conv4_w  = (const float*)d_in[9];
    const float* conv4_b  = (const float*)d_in[10];
    const float* fc1_w    = (const float*)d_in[11];
    const float* fc1_b    = (const float*)d_in[12];
    const float* fc2_w    = (const float*)d_in[13];
    const float* fc2_b    = (const float*)d_in[14];
    const float* fc3_w    = (const float*)d_in[15];
    const float* fc3_b    = (const float*)d_in[16];
    const float* fc4_ea_w = (const float*)d_in[17];
    const float* fc4_ea_b = (const float*)d_in[18];
    const float* fc4_ev_w = (const float*)d_in[19];
    const float* fc4_ev_b = (const float*)d_in[20];

    char* ws = (char*)d_ws;
    // ---- weights & small buffers: [0, 14,418,176) -- never overwritten ----
    bf16_t* w1A    = (bf16_t*)(ws + 0);          //    262,144 conv1 frags
    bf16_t* w2A    = (bf16_t*)(ws + 262144);     //  4,194,304 conv2 frags
    bf16_t* w3A    = (bf16_t*)(ws + 4456448);    //    524,288 conv3 frags
    bf16_t* w4A    = (bf16_t*)(ws + 4980736);    //    524,288 conv4 frags
    bf16_t* w4p    = (bf16_t*)(ws + 5505024);    //    524,288 conv4c generic
    bf16_t* fc2wp  = (bf16_t*)(ws + 6029312);    //  6,553,600
    bf16_t* fc3wp  = (bf16_t*)(ws + 12582912);   //    524,288
    float*  scal   = (float*) (ws + 13107200);   //        256
    float*  part   = (float*) (ws + 13107456);   //  1,048,576
    bf16_t* x2fc   = (bf16_t*)(ws + 14156032);   //    131,072
    bf16_t* x3fc   = (bf16_t*)(ws + 14287104);   //    131,072
    // ---- activations (reuse only where producer strictly after consumer) --
    bf16_t* a0     = (bf16_t*)(ws + 14418176);   // 10,240,000 input NHWC
    bf16_t* x4a    = (bf16_t*)(ws + 14418176);   //  9,437,184 (a0 dead after conv1)
    bf16_t* x1     = (bf16_t*)(ws + 24658176);   // 39,002,112
    bf16_t* x4b    = (bf16_t*)(ws + 24658176);   //  4,734,976 (x1 dead after conv2)
    bf16_t* x4c    = (bf16_t*)(ws + 29393152);   //  1,638,400 (ditto; disjoint from x4b)
    bf16_t* x2     = (bf16_t*)(ws + 63660288);   // 23,658,496
    bf16_t* x3     = (bf16_t*)(ws + 87318784);   // 15,745,024 -> end 103,063,808
    (void)in_sizes; (void)n_in; (void)out_size; (void)ws_size;

    // weight packing + input layout conversion
    pack_wA<4, 32, 32> <<<dim3(64),   256, 0, stream>>>(conv1_w, w1A);
    pack_wA<32, 64, 32><<<dim3(1024), 256, 0, stream>>>(conv2_w, w2A);
    pack_wA<64, 64, 8> <<<dim3(128),  256, 0, stream>>>(conv3_w, w3A);
    pack_wA<64, 64, 8> <<<dim3(128),  256, 0, stream>>>(conv4_w, w4A);
    pack_w<64><<<dim3(16),   256, 0, stream>>>(conv4_w, w4p, 64, 64);
    pack_w<64><<<dim3(200),  256, 0, stream>>>(fc2_w, fc2wp, 512, 100);
    pack_w<1> <<<dim3(1024), 256, 0, stream>>>(fc3_w, fc3wp, 512, 512);
    pack_w<4> <<<dim3(1024), 256, 0, stream>>>(state_m, a0, 128, 10000);
    fc1_scalar<<<1, 64, 0, stream>>>(state_g, state_v, fc1_w, fc1_b, scal);

    // conv chain  conv_rr<CIN,COUT,W,K,OW,WMT,NSLOT,ADD_SCALAR>
    conv_rr<4, 32, 100, 32, 69, 3, 8, 0>
        <<<dim3(13, 1, 128), 256, 0, stream>>>(a0, w1A, conv1_b, x1, nullptr);
    conv_rr<32, 64, 69, 32, 38, 3, 12, 0>
        <<<dim3(4, 1, 128), 256, 0, stream>>>(x1, w2A, conv2_b, x2, nullptr);
    conv_rr<64, 64, 38, 8, 31, 2, 11, 1>
        <<<dim3(4, 1, 128), 256, 0, stream>>>(x2, w3A, conv3_b, x3, scal);
    conv_rr<64, 64, 31, 8, 24, 2, 13, 0>
        <<<dim3(3, 1, 128), 256, 0, stream>>>(x3, w4A, conv4_b, x4a, nullptr);
    conv_rr<64, 64, 24, 8, 17, 2, 17, 0>
        <<<dim3(2, 1, 128), 256, 0, stream>>>(x4a, w4A, conv4_b, x4b, nullptr);
    conv_mfma<64, 64, 17, 8, 10, 32, 1, 0, true>
        <<<dim3(2, 2, 128), 256, 0, stream>>>(x4b, w4p, conv4_b, x4c, nullptr);

    // FC head
    fc2_kernel<<<dim3(8, 4), 256, 0, stream>>>(x4c, fc2wp, part);
    fc2_reduce<<<dim3(256), 256, 0, stream>>>(part, fc2_b, x2fc);
    fc3_kernel<<<dim3(8), 256, 0, stream>>>(x2fc, fc3wp, fc3_b, x3fc);
    final_kernel<<<dim3(128), 64, 0, stream>>>(x3fc, fc4_ea_w, fc4_ea_b,
                                               fc4_ev_w, fc4_ev_b, (float*)d_out);
}

// Round 5
// 1293.295 us; speedup vs baseline: 2.2305x; 1.4192x over previous
//
#include <hip/hip_runtime.h>
#include <stdint.h>

// ---------------------------------------------------------------------------
// Dueling-DQN forward on MI355X. Round 5: conv_rr LDS layout transposed into
// 16B chunk-planes (lds[c][q]) so B-fragment reads are lane-contiguous and
// bank-conflict-free by construction; explicit 1-deep A/B register pipeline.
// ---------------------------------------------------------------------------

using bf16_t = __bf16;
using bf16x8 = __attribute__((ext_vector_type(8))) __bf16;
using bf16x4 = __attribute__((ext_vector_type(4))) __bf16;
using f32x4  = __attribute__((ext_vector_type(4))) float;
using f32x16 = __attribute__((ext_vector_type(16))) float;

__device__ __forceinline__ f32x4 mfma16(bf16x8 a, bf16x8 b, f32x4 c) {
    return __builtin_amdgcn_mfma_f32_16x16x32_bf16(a, b, c, 0, 0, 0);
}
__device__ __forceinline__ f32x16 mfma32(bf16x8 a, bf16x8 b, f32x16 c) {
    return __builtin_amdgcn_mfma_f32_32x32x16_bf16(a, b, c, 0, 0, 0);
}

template<bool A16>
__device__ __forceinline__ bf16x8 load_frag(const bf16_t* p) {
    if constexpr (A16) {
        return *reinterpret_cast<const bf16x8*>(p);
    } else {
        union { bf16x8 v; uint64_t u[2]; } r;
        r.u[0] = *reinterpret_cast<const uint64_t*>(p);
        r.u[1] = *reinterpret_cast<const uint64_t*>(p + 4);
        return r.v;
    }
}

// ---------------------------------------------------------------------------
// Generic pack: dst[cout][khw][cin] = (bf16)src[cout][cin][khw]
// ---------------------------------------------------------------------------
template<int CIN>
__global__ void pack_w(const float* __restrict__ src, bf16_t* __restrict__ dst,
                       int COUT, int KK) {
    int total = COUT * KK;
    for (int t = blockIdx.x * blockDim.x + threadIdx.x; t < total;
         t += gridDim.x * blockDim.x) {
        int cout = t / KK;
        int khw  = t - cout * KK;
        alignas(16) bf16_t tmp[CIN];
        #pragma unroll
        for (int c = 0; c < CIN; ++c)
            tmp[c] = (bf16_t)src[((size_t)cout * CIN + c) * KK + khw];
        bf16_t* d = dst + (size_t)t * CIN;
        if constexpr (CIN == 1) {
            d[0] = tmp[0];
        } else if constexpr (CIN == 4) {
            *reinterpret_cast<uint2*>(d) = *reinterpret_cast<const uint2*>(tmp);
        } else {
            #pragma unroll
            for (int c = 0; c < CIN; c += 8)
                *reinterpret_cast<uint4*>(d + c) =
                    *reinterpret_cast<const uint4*>(tmp + c);
        }
    }
}

// ---------------------------------------------------------------------------
// A-fragment pack for 32x32x16 MFMA conv: frag f = (kh*S + s)*NT + n holds
// couts n*32+(l&31); k = s*16 + (l>>5)*8 + e; k -> (kw = k/CIN, cin = k%CIN).
// Source OIHW [COUT][CIN][K][K]. dst[f*512 + lane*8 + e], 1KB per frag.
// ---------------------------------------------------------------------------
template<int CIN, int COUT, int K>
__global__ void pack_wA(const float* __restrict__ src, bf16_t* __restrict__ dst) {
    constexpr int S  = K * CIN / 16;
    constexpr int NT = COUT / 32;
    int t = blockIdx.x * 256 + threadIdx.x;
    int l  = t & 63;
    int f  = t >> 6;
    int n  = f % NT;
    int fs = f / NT;
    int s  = fs % S;
    int kh = fs / S;
    if (kh >= K) return;
    int cout = n * 32 + (l & 31);
    int k0   = s * 16 + (l >> 5) * 8;
    alignas(16) bf16_t tmp[8];
    #pragma unroll
    for (int e = 0; e < 8; ++e) {
        int k   = k0 + e;
        int kw  = k / CIN;
        int cin = k % CIN;
        tmp[e] = (bf16_t)src[(((size_t)cout * CIN + cin) * K + kh) * K + kw];
    }
    *reinterpret_cast<uint4*>(dst + (size_t)t * 8) =
        *reinterpret_cast<const uint4*>(tmp);
}

// scalar = relu(fc1(concat(g[0],v[0]))[30])
__global__ void fc1_scalar(const float* __restrict__ g, const float* __restrict__ v,
                           const float* __restrict__ w, const float* __restrict__ b,
                           float* __restrict__ outp) {
    if (threadIdx.x == 0 && blockIdx.x == 0) {
        float s = b[30] + g[0] * w[120] + g[1] * w[121] + v[0] * w[122] + v[1] * w[123];
        *outp = s > 0.f ? s : 0.f;
    }
}

// ---------------------------------------------------------------------------
// Rolling-row LDS implicit-GEMM conv, 32x32x16 MFMA.
// TR layout (CIN>=16): each staged row is stored as NCH chunk-planes:
//   lds[slot][c][q] (16B entries), c = chunk-in-pixel, q = pixel column.
//   B-read for k-step s: c=(s%SPP)*2+h, q=ow+s/SPP -> lane-contiguous 16B.
// conv1 (CIN=4) keeps the linear row layout (8B pixels ~2-way, free).
// ---------------------------------------------------------------------------
template<int CIN, int COUT, int W, int K, int OW, int WMT, int NSLOT,
         int ADD_SCALAR>
__global__ __launch_bounds__(256, 2) void conv_rr(
    const bf16_t* __restrict__ in, const bf16_t* __restrict__ wA,
    const float* __restrict__ bias, bf16_t* __restrict__ out,
    const float* __restrict__ scal) {
    constexpr int  P     = OW * OW;
    constexpr int  PIXB  = CIN * 2;
    constexpr int  ROWB  = W * PIXB;
    constexpr bool TR    = (CIN >= 16);
    constexpr int  NCH   = TR ? PIXB / 16 : 1;      // chunk-planes per pixel
    constexpr int  SPP   = TR ? NCH / 2 : 1;        // k-steps per pixel
    constexpr int  PS    = TR ? (W + 1) * 16 : 0;   // plane stride (padded)
    constexpr int  SLOTB = TR ? NCH * PS : ROWB;    // bytes per row-slot
    constexpr int  LDSB  = NSLOT * SLOTB;
    constexpr int  S     = K * CIN / 16;
    constexpr int  NT    = COUT / 32;
    constexpr int  BPX   = WMT * 32 * 4;
    constexpr int  CH    = ROWB / 16;               // 16B chunks per row
    constexpr int  NLD   = (CH + 255) / 256;
    __shared__ __align__(16) char smem[LDSB];

    const int tid  = threadIdx.x;
    const int wave = tid >> 6, lane = tid & 63;
    const int l31  = lane & 31, h = lane >> 5;
    const int img  = blockIdx.z;
    const int p0   = blockIdx.x * BPX;

    const char* inb = (const char*)(in + (size_t)img * ((size_t)W * W * CIN));

    const int r0 = p0 / OW;
    int plast = p0 + BPX - 1; if (plast > P - 1) plast = P - 1;
    const int r1 = plast / OW;

    // staging chunk->LDS offset for this thread (same map for all rows)
    int woff[NLD];
    #pragma unroll
    for (int i = 0; i < NLD; ++i) {
        int c = i * 256 + tid;
        if (c < CH) woff[i] = TR ? (c % NCH) * PS + (c / NCH) * 16 : c * 16;
        else        woff[i] = 0;
    }

    int pix[WMT], ldsadr[WMT];
    #pragma unroll
    for (int m = 0; m < WMT; ++m) {
        int p  = p0 + (wave * WMT + m) * 32 + l31;
        pix[m] = p;
        int pc = p < P ? p : P - 1;
        int oh = pc / OW;
        int ow = pc - oh * OW;
        ldsadr[m] = (oh % NSLOT) * SLOTB +
                    (TR ? ow * 16 + h * PS : ow * PIXB + h * 16);
    }

    // prologue: stage rows r0..r1
    for (int r = r0; r <= r1; ++r) {
        const char* g = inb + (size_t)r * ROWB;
        int base = (r % NSLOT) * SLOTB;
        for (int c = tid; c < CH; c += 256) {
            bf16x8 v = *reinterpret_cast<const bf16x8*>(g + c * 16);
            int off = TR ? (c % NCH) * PS + (c / NCH) * 16 : c * 16;
            *reinterpret_cast<bf16x8*>(smem + base + off) = v;
        }
    }
    __syncthreads();

    f32x16 acc[WMT][NT] = {};

    int wsl = (r1 + 1) % NSLOT;
    const char* gpre = inb + (size_t)(r1 + 1) * ROWB;
    const bf16_t* wl = wA + lane * 8;

    for (int kh = 0; kh < K; ++kh) {
        bf16x8 stv[NLD];
        const bool pf = kh < K - 1;
        if (pf) {                                    // T14: issue early
            #pragma unroll
            for (int i = 0; i < NLD; ++i) {
                int c = i * 256 + tid;
                if (c < CH) stv[i] = *reinterpret_cast<const bf16x8*>(gpre + c * 16);
            }
        }
        const bf16_t* ap = wl + (size_t)kh * (S * NT * 512);

        // ---- 1-deep software pipeline over s ----
        auto bread = [&](int m, int s) -> bf16x8 {
            int a = TR ? ldsadr[m] + (s % SPP) * (2 * PS) + (s / SPP) * 16
                       : ldsadr[m] + s * 32;
            return *reinterpret_cast<const bf16x8*>(smem + a);
        };
        bf16x8 bcur[WMT], acur[NT];
        #pragma unroll
        for (int m = 0; m < WMT; ++m) bcur[m] = bread(m, 0);
        #pragma unroll
        for (int n = 0; n < NT; ++n)
            acur[n] = *reinterpret_cast<const bf16x8*>(ap + n * 512);

        #pragma unroll 8
        for (int s = 0; s < S - 1; ++s) {
            bf16x8 bnx[WMT], anx[NT];
            #pragma unroll
            for (int m = 0; m < WMT; ++m) bnx[m] = bread(m, s + 1);
            #pragma unroll
            for (int n = 0; n < NT; ++n)
                anx[n] = *reinterpret_cast<const bf16x8*>(ap + ((s + 1) * NT + n) * 512);
            #pragma unroll
            for (int m = 0; m < WMT; ++m)
                #pragma unroll
                for (int n = 0; n < NT; ++n)
                    acc[m][n] = mfma32(acur[n], bcur[m], acc[m][n]);
            #pragma unroll
            for (int m = 0; m < WMT; ++m) bcur[m] = bnx[m];
            #pragma unroll
            for (int n = 0; n < NT; ++n) acur[n] = anx[n];
        }
        #pragma unroll
        for (int m = 0; m < WMT; ++m)
            #pragma unroll
            for (int n = 0; n < NT; ++n)
                acc[m][n] = mfma32(acur[n], bcur[m], acc[m][n]);

        if (pf) {                                    // write-late
            int wb0 = wsl * SLOTB;
            #pragma unroll
            for (int i = 0; i < NLD; ++i) {
                int c = i * 256 + tid;
                if (c < CH)
                    *reinterpret_cast<bf16x8*>(smem + wb0 + woff[i]) = stv[i];
            }
            gpre += ROWB;
            wsl = (wsl + 1 == NSLOT) ? 0 : wsl + 1;
        }
        __syncthreads();
        #pragma unroll
        for (int m = 0; m < WMT; ++m) {
            int a2 = ldsadr[m] + SLOTB;
            ldsadr[m] = a2 >= LDSB ? a2 - LDSB : a2;
        }
    }

    float sc = 0.f;
    if constexpr (ADD_SCALAR) sc = *scal;
    bf16_t* outb = out + (size_t)img * ((size_t)P * COUT);
    #pragma unroll
    for (int m = 0; m < WMT; ++m) {
        if (pix[m] < P) {
            #pragma unroll
            for (int n = 0; n < NT; ++n) {
                #pragma unroll
                for (int rg = 0; rg < 4; ++rg) {
                    int cb = n * 32 + rg * 8 + h * 4;
                    f32x4 bv = *reinterpret_cast<const f32x4*>(bias + cb);
                    union { bf16x4 v; uint2 u; } o;
                    #pragma unroll
                    for (int j = 0; j < 4; ++j) {
                        float x = acc[m][n][rg * 4 + j] + bv[j];
                        x = x > 0.f ? x : 0.f;
                        x += sc;
                        o.v[j] = (bf16_t)x;
                    }
                    *reinterpret_cast<uint2*>(outb + (size_t)pix[m] * COUT + cb) = o.u;
                }
            }
        }
    }
}

// ---------------------------------------------------------------------------
// Generic implicit-GEMM conv (16x16x32) via global loads — used for conv4c.
// ---------------------------------------------------------------------------
template<int CIN, int COUT, int W, int K, int OW, int NBLK, int WMT,
         int ADD_SCALAR, bool A16>
__global__ __launch_bounds__(256, 2) void conv_mfma(
    const bf16_t* __restrict__ in, const bf16_t* __restrict__ wp,
    const float* __restrict__ bias, bf16_t* __restrict__ out,
    const float* __restrict__ scal) {
    constexpr int P    = OW * OW;
    constexpr int KCIN = K * CIN;
    constexpr int KTOT = K * KCIN;
    constexpr int RS   = KCIN / 32;
    constexpr int NT   = NBLK / 16;
    constexpr int BMT  = WMT * 4;

    const int b     = blockIdx.z;
    const int cout0 = blockIdx.y * NBLK;
    const int wave  = threadIdx.x >> 6;
    const int lane  = threadIdx.x & 63;
    const int l15   = lane & 15;
    const int l4    = lane >> 4;
    const int mt0   = blockIdx.x * BMT + wave * WMT;

    const bf16_t* inb = in + (size_t)b * (W * W * CIN);

    int      pix[WMT];
    uint32_t pb[WMT];
    #pragma unroll
    for (int m = 0; m < WMT; ++m) {
        int p  = (mt0 + m) * 16 + l15;
        pix[m] = p;
        int pc = p < P ? p : P - 1;
        int oh = pc / OW;
        int ow = pc - oh * OW;
        pb[m]  = (uint32_t)(oh * W + ow) * CIN;
    }
    uint32_t wb[NT];
    #pragma unroll
    for (int n = 0; n < NT; ++n)
        wb[n] = (uint32_t)(cout0 + n * 16 + l15) * KTOT + (uint32_t)l4 * 8u;

    f32x4 acc[WMT][NT];
    #pragma unroll
    for (int m = 0; m < WMT; ++m)
        #pragma unroll
        for (int n = 0; n < NT; ++n)
            acc[m][n] = f32x4{0.f, 0.f, 0.f, 0.f};

    uint32_t bofs = (uint32_t)l4 * 8u;
    for (int kh = 0; kh < K; ++kh) {
        #pragma unroll
        for (int s = 0; s < RS; ++s) {
            bf16x8 af[NT];
            #pragma unroll
            for (int n = 0; n < NT; ++n)
                af[n] = load_frag<true>(wp + wb[n] + kh * KCIN + s * 32);
            #pragma unroll
            for (int m = 0; m < WMT; ++m) {
                bf16x8 bfr = load_frag<A16>(inb + pb[m] + bofs + s * 32);
                #pragma unroll
                for (int n = 0; n < NT; ++n)
                    acc[m][n] = mfma16(af[n], bfr, acc[m][n]);
            }
        }
        bofs += (uint32_t)(W * CIN);
    }

    float sc = 0.f;
    if constexpr (ADD_SCALAR) sc = *scal;
    bf16_t* outb = out + (size_t)b * P * COUT;
    #pragma unroll
    for (int n = 0; n < NT; ++n) {
        const int cb = cout0 + n * 16 + l4 * 4;
        f32x4 bv = *reinterpret_cast<const f32x4*>(bias + cb);
        #pragma unroll
        for (int m = 0; m < WMT; ++m) {
            if (pix[m] < P) {
                f32x4 v = acc[m][n];
                union { bf16x4 h; uint2 u; } st;
                #pragma unroll
                for (int r = 0; r < 4; ++r) {
                    float x = v[r] + bv[r];
                    x = x > 0.f ? x : 0.f;
                    x += sc;
                    st.h[r] = (bf16_t)x;
                }
                *reinterpret_cast<uint2*>(outb + (size_t)pix[m] * COUT + cb) = st.u;
            }
        }
    }
}

// ---------------------------------------------------------------------------
// fc2: [128,6400]x[512,6400]^T, K-split x4 into f32 partials.
// ---------------------------------------------------------------------------
__global__ __launch_bounds__(256, 2) void fc2_kernel(
    const bf16_t* __restrict__ x, const bf16_t* __restrict__ w,
    float* __restrict__ part) {
    const int nb = blockIdx.x, kc = blockIdx.y;
    const int wave = threadIdx.x >> 6, lane = threadIdx.x & 63;
    const int l15 = lane & 15, l4 = lane >> 4;
    const int wm = wave & 1, wn = wave >> 1;

    f32x4 acc[4][2];
    #pragma unroll
    for (int m = 0; m < 4; ++m)
        #pragma unroll
        for (int n = 0; n < 2; ++n) acc[m][n] = f32x4{0.f, 0.f, 0.f, 0.f};

    uint32_t xb[4], wbf[2];
    #pragma unroll
    for (int m = 0; m < 4; ++m)
        xb[m] = (uint32_t)(16 * (wm * 4 + m) + l15) * 6400u + kc * 1600u + l4 * 8u;
    #pragma unroll
    for (int n = 0; n < 2; ++n)
        wbf[n] = (uint32_t)(nb * 64 + wn * 32 + n * 16 + l15) * 6400u + kc * 1600u + l4 * 8u;

    for (int s = 0; s < 50; ++s) {
        bf16x8 af[2];
        #pragma unroll
        for (int n = 0; n < 2; ++n)
            af[n] = load_frag<true>(w + wbf[n] + s * 32);
        #pragma unroll
        for (int m = 0; m < 4; ++m) {
            bf16x8 bfr = load_frag<true>(x + xb[m] + s * 32);
            #pragma unroll
            for (int n = 0; n < 2; ++n)
                acc[m][n] = mfma16(af[n], bfr, acc[m][n]);
        }
    }
    #pragma unroll
    for (int m = 0; m < 4; ++m) {
        int bcol = 16 * (wm * 4 + m) + l15;
        #pragma unroll
        for (int n = 0; n < 2; ++n) {
            int cf = nb * 64 + wn * 32 + n * 16 + l4 * 4;
            *reinterpret_cast<f32x4*>(part + ((size_t)kc * 128 + bcol) * 512 + cf) =
                acc[m][n];
        }
    }
}

__global__ void fc2_reduce(const float* __restrict__ part,
                           const float* __restrict__ bias,
                           bf16_t* __restrict__ xo) {
    int t = blockIdx.x * 256 + threadIdx.x;
    if (t < 128 * 512) {
        int b = t >> 9, co = t & 511;
        float s = bias[co];
        #pragma unroll
        for (int kc = 0; kc < 4; ++kc) s += part[((size_t)kc * 128 + b) * 512 + co];
        xo[t] = (bf16_t)(s > 0.f ? s : 0.f);
    }
}

__global__ __launch_bounds__(256, 2) void fc3_kernel(
    const bf16_t* __restrict__ x, const bf16_t* __restrict__ w,
    const float* __restrict__ bias, bf16_t* __restrict__ xo) {
    const int nb = blockIdx.x;
    const int wave = threadIdx.x >> 6, lane = threadIdx.x & 63;
    const int l15 = lane & 15, l4 = lane >> 4;

    f32x4 acc[2][4];
    #pragma unroll
    for (int m = 0; m < 2; ++m)
        #pragma unroll
        for (int n = 0; n < 4; ++n) acc[m][n] = f32x4{0.f, 0.f, 0.f, 0.f};

    uint32_t xb[2], wbf[4];
    #pragma unroll
    for (int m = 0; m < 2; ++m)
        xb[m] = (uint32_t)(16 * (wave * 2 + m) + l15) * 512u + l4 * 8u;
    #pragma unroll
    for (int n = 0; n < 4; ++n)
        wbf[n] = (uint32_t)(nb * 64 + n * 16 + l15) * 512u + l4 * 8u;

    #pragma unroll
    for (int s = 0; s < 16; ++s) {
        bf16x8 af[4];
        #pragma unroll
        for (int n = 0; n < 4; ++n) af[n] = load_frag<true>(w + wbf[n] + s * 32);
        #pragma unroll
        for (int m = 0; m < 2; ++m) {
            bf16x8 bfr = load_frag<true>(x + xb[m] + s * 32);
            #pragma unroll
            for (int n = 0; n < 4; ++n)
                acc[m][n] = mfma16(af[n], bfr, acc[m][n]);
        }
    }
    #pragma unroll
    for (int n = 0; n < 4; ++n) {
        int cf = nb * 64 + n * 16 + l4 * 4;
        f32x4 bv = *reinterpret_cast<const f32x4*>(bias + cf);
        #pragma unroll
        for (int m = 0; m < 2; ++m) {
            int brow = 16 * (wave * 2 + m) + l15;
            union { bf16x4 h; uint2 u; } st;
            #pragma unroll
            for (int r = 0; r < 4; ++r) {
                float v = acc[m][n][r] + bv[r];
                st.h[r] = (bf16_t)(v > 0.f ? v : 0.f);
            }
            *reinterpret_cast<uint2*>(xo + (size_t)brow * 512 + cf) = st.u;
        }
    }
}

__global__ void final_kernel(const bf16_t* __restrict__ x,
                             const float* __restrict__ eaw, const float* __restrict__ eab,
                             const float* __restrict__ evw, const float* __restrict__ evb,
                             float* __restrict__ out) {
    int b = blockIdx.x, lane = threadIdx.x;
    bf16x8 xv = *reinterpret_cast<const bf16x8*>(x + (size_t)b * 512 + lane * 8);
    float xs[8];
    #pragma unroll
    for (int i = 0; i < 8; ++i) xs[i] = (float)xv[i];
    float a[10];
    #pragma unroll
    for (int j = 0; j < 10; ++j) {
        const float* wr = (j < 9) ? (eaw + (size_t)j * 512) : evw;
        const f32x4* w4 = reinterpret_cast<const f32x4*>(wr + lane * 8);
        f32x4 w0 = w4[0], w1 = w4[1];
        float s = 0.f;
        #pragma unroll
        for (int i = 0; i < 4; ++i) s += xs[i] * w0[i];
        #pragma unroll
        for (int i = 0; i < 4; ++i) s += xs[4 + i] * w1[i];
        a[j] = s;
    }
    #pragma unroll
    for (int off = 1; off < 64; off <<= 1)
        #pragma unroll
        for (int j = 0; j < 10; ++j) a[j] += __shfl_xor(a[j], off);
    if (lane < 9) {
        float val  = a[9] + evb[0];
        float mean = 0.f;
        #pragma unroll
        for (int j = 0; j < 9; ++j) mean += a[j] + eab[j];
        mean *= (1.f / 9.f);
        out[b * 9 + lane] = a[lane] + eab[lane] + val - mean;
    }
}

// ---------------------------------------------------------------------------
extern "C" void kernel_launch(void* const* d_in, const int* in_sizes, int n_in,
                              void* d_out, int out_size, void* d_ws, size_t ws_size,
                              hipStream_t stream) {
    const float* state_m  = (const float*)d_in[0];
    const float* state_g  = (const float*)d_in[1];
    const float* state_v  = (const float*)d_in[2];
    const float* conv1_w  = (const float*)d_in[3];
    const float* conv1_b  = (const float*)d_in[4];
    const float* conv2_w  = (const float*)d_in[5];
    const float* conv2_b  = (const float*)d_in[6];
    const float* conv3_w  = (const float*)d_in[7];
    const float* conv3_b  = (const float*)d_in[8];
    const float* conv4_w  = (const float*)d_in[9];
    const float* conv4_b  = (const float*)d_in[10];
    const float* fc1_w    = (const float*)d_in[11];
    const float* fc1_b    = (const float*)d_in[12];
    const float* fc2_w    = (const float*)d_in[13];
    const float* fc2_b    = (const float*)d_in[14];
    const float* fc3_w    = (const float*)d_in[15];
    const float* fc3_b    = (const float*)d_in[16];
    const float* fc4_ea_w = (const float*)d_in[17];
    const float* fc4_ea_b = (const float*)d_in[18];
    const float* fc4_ev_w = (const float*)d_in[19];
    const float* fc4_ev_b = (const float*)d_in[20];

    char* ws = (char*)d_ws;
    // ---- weights & small buffers: [0, 14,418,176) -- never overwritten ----
    bf16_t* w1A    = (bf16_t*)(ws + 0);          //    262,144 conv1 frags
    bf16_t* w2A    = (bf16_t*)(ws + 262144);     //  4,194,304 conv2 frags
    bf16_t* w3A    = (bf16_t*)(ws + 4456448);    //    524,288 conv3 frags
    bf16_t* w4A    = (bf16_t*)(ws + 4980736);    //    524,288 conv4 frags
    bf16_t* w4p    = (bf16_t*)(ws + 5505024);    //    524,288 conv4c generic
    bf16_t* fc2wp  = (bf16_t*)(ws + 6029312);    //  6,553,600
    bf16_t* fc3wp  = (bf16_t*)(ws + 12582912);   //    524,288
    float*  scal   = (float*) (ws + 13107200);   //        256
    float*  part   = (float*) (ws + 13107456);   //  1,048,576
    bf16_t* x2fc   = (bf16_t*)(ws + 14156032);   //    131,072
    bf16_t* x3fc   = (bf16_t*)(ws + 14287104);   //    131,072
    // ---- activations (reuse only where producer strictly after consumer) --
    bf16_t* a0     = (bf16_t*)(ws + 14418176);   // 10,240,000 input NHWC
    bf16_t* x4a    = (bf16_t*)(ws + 14418176);   //  9,437,184 (a0 dead after conv1)
    bf16_t* x1     = (bf16_t*)(ws + 24658176);   // 39,002,112
    bf16_t* x4b    = (bf16_t*)(ws + 24658176);   //  4,734,976 (x1 dead after conv2)
    bf16_t* x4c    = (bf16_t*)(ws + 29393152);   //  1,638,400 (ditto; disjoint from x4b)
    bf16_t* x2     = (bf16_t*)(ws + 63660288);   // 23,658,496
    bf16_t* x3     = (bf16_t*)(ws + 87318784);   // 15,745,024 -> end 103,063,808
    (void)in_sizes; (void)n_in; (void)out_size; (void)ws_size;

    // weight packing + input layout conversion
    pack_wA<4, 32, 32> <<<dim3(64),   256, 0, stream>>>(conv1_w, w1A);
    pack_wA<32, 64, 32><<<dim3(1024), 256, 0, stream>>>(conv2_w, w2A);
    pack_wA<64, 64, 8> <<<dim3(128),  256, 0, stream>>>(conv3_w, w3A);
    pack_wA<64, 64, 8> <<<dim3(128),  256, 0, stream>>>(conv4_w, w4A);
    pack_w<64><<<dim3(16),   256, 0, stream>>>(conv4_w, w4p, 64, 64);
    pack_w<64><<<dim3(200),  256, 0, stream>>>(fc2_w, fc2wp, 512, 100);
    pack_w<1> <<<dim3(1024), 256, 0, stream>>>(fc3_w, fc3wp, 512, 512);
    pack_w<4> <<<dim3(1024), 256, 0, stream>>>(state_m, a0, 128, 10000);
    fc1_scalar<<<1, 64, 0, stream>>>(state_g, state_v, fc1_w, fc1_b, scal);

    // conv chain  conv_rr<CIN,COUT,W,K,OW,WMT,NSLOT,ADD_SCALAR>
    conv_rr<4, 32, 100, 32, 69, 3, 8, 0>
        <<<dim3(13, 1, 128), 256, 0, stream>>>(a0, w1A, conv1_b, x1, nullptr);
    conv_rr<32, 64, 69, 32, 38, 3, 12, 0>
        <<<dim3(4, 1, 128), 256, 0, stream>>>(x1, w2A, conv2_b, x2, nullptr);
    conv_rr<64, 64, 38, 8, 31, 2, 11, 1>
        <<<dim3(4, 1, 128), 256, 0, stream>>>(x2, w3A, conv3_b, x3, scal);
    conv_rr<64, 64, 31, 8, 24, 2, 13, 0>
        <<<dim3(3, 1, 128), 256, 0, stream>>>(x3, w4A, conv4_b, x4a, nullptr);
    conv_rr<64, 64, 24, 8, 17, 2, 17, 0>
        <<<dim3(2, 1, 128), 256, 0, stream>>>(x4a, w4A, conv4_b, x4b, nullptr);
    conv_mfma<64, 64, 17, 8, 10, 32, 1, 0, true>
        <<<dim3(2, 2, 128), 256, 0, stream>>>(x4b, w4p, conv4_b, x4c, nullptr);

    // FC head
    fc2_kernel<<<dim3(8, 4), 256, 0, stream>>>(x4c, fc2wp, part);
    fc2_reduce<<<dim3(256), 256, 0, stream>>>(part, fc2_b, x2fc);
    fc3_kernel<<<dim3(8), 256, 0, stream>>>(x2fc, fc3wp, fc3_b, x3fc);
    final_kernel<<<dim3(128), 64, 0, stream>>>(x3fc, fc4_ea_w, fc4_ea_b,
                                               fc4_ev_w, fc4_ev_b, (float*)d_out);
}